// Round 1
// baseline (218.578 us; speedup 1.0000x reference)
//
#include <hip/hip_runtime.h>
#include <hip/hip_cooperative_groups.h>

namespace cg = cooperative_groups;

typedef __bf16 bf16_t;
typedef __bf16 bf16x4 __attribute__((ext_vector_type(4)));
typedef __bf16 bf16x8 __attribute__((ext_vector_type(8)));
typedef float f32x4 __attribute__((ext_vector_type(4)));

#define T_SEQ 1024
#define EMB   512
#define NH    8
#define HD    64
#define BATCH 2
#define NBH   (BATCH*NH)      // 16
#define CHUNK 64
#define NCHUNK (T_SEQ/CHUNK)  // 16
#define NBLK  (NBH*NCHUNK)    // 256
#define LDA   72              // padded LDS row stride (chunk_out phase)
#define LDK   68              // padded LDS row stride (qkv_sum handoff)

// Identity: with ang_t = (pi/2)*t/T,
//   q_cos[t].k_cos[s] + q_sin[t].k_sin[s] = (q'[t].k'[s]) * cos(ang_t - ang_s)
//
// R13: single cooperative kernel. The 4 proven phase bodies (cvt3, qkv+sum,
// chunk_out, out_gemm) are unchanged; 4 dispatches -> 1 dispatch with 3
// grid.sync()s. All phases used grid<=256 blocks x 256 threads = 1 block/CU,
// so co-residency holds. LDS is a union (P2 = 57KB max, < 64KB/block).

struct P1s {                    // qkv_sum handoff
    bf16_t sk[CHUNK * LDK];
    bf16_t sv[CHUNK * LDK];
    float  cwt[CHUNK], swt[CHUNK];
};
struct P2s {                    // chunk_out working set
    bf16_t sq [CHUNK * LDA];
    bf16_t sk [CHUNK * LDA];
    bf16_t svT[CHUNK * LDA];
    bf16_t sct[CHUNK * LDA];
    bf16_t sst[CHUNK * LDA];
    bf16_t sp [CHUNK * LDA];
    float  cwt[CHUNK], swt[CHUNK], cosd[CHUNK];
    float  zcl[CHUNK], zsl[CHUNK], nrm[CHUNK];
};
union SMemU { P1s p1; P2s p2; };

__global__ __launch_bounds__(256) void fused_kernel(
    const float* __restrict__ x,  const float* __restrict__ wq,
    const float* __restrict__ wo, const float* __restrict__ b_qkv,
    const float* __restrict__ b_out,
    bf16_t* __restrict__ xb, bf16_t* __restrict__ wqb, bf16_t* __restrict__ wob,
    bf16_t* __restrict__ qq, bf16_t* __restrict__ kk, bf16_t* __restrict__ vv,
    bf16_t* __restrict__ Ssc, bf16_t* __restrict__ Sss,
    float* __restrict__ zc, float* __restrict__ zs,
    bf16_t* __restrict__ Y, float* __restrict__ out)
{
    __shared__ __align__(16) SMemU sm;
    cg::grid_group grid = cg::this_grid();
    const int tid = threadIdx.x;
    const int blk = blockIdx.x;

    // ---------------- phase 0: fp32 -> bf16 convert (grid-stride) ----------
    for (int i = blk * 256 + tid; i < 524288; i += NBLK * 256) {
        const float* s; bf16_t* d; int off;
        if (i < 262144)      { s = x;  d = xb;  off = i; }
        else if (i < 458752) { s = wq; d = wqb; off = i - 262144; }
        else                 { s = wo; d = wob; off = i - 458752; }
        float4 v = ((const float4*)s)[off];
        bf16x4 o;
        o[0] = (bf16_t)v.x; o[1] = (bf16_t)v.y;
        o[2] = (bf16_t)v.z; o[3] = (bf16_t)v.w;
        ((bf16x4*)d)[off] = o;
    }
    grid.sync();

    // ---------------- phase 1: qkv GEMM + chunk_sum ------------------------
    {
        bf16_t* sk  = sm.p1.sk;
        bf16_t* sv  = sm.p1.sv;
        float*  cwt = sm.p1.cwt;
        float*  swt = sm.p1.swt;

        const int m0 = (blk & 31) * 64;
        const int h  = blk >> 5;
        const int b  = m0 >> 10;
        const int ch = (m0 & 1023) >> 6;
        const int sblk = (b * NH + h) * NCHUNK + ch;

        if (tid < CHUNK) {
            int tg = ch * CHUNK + tid;
            float ang = 1.5707963267948966f * (float)tg * (1.0f / (float)T_SEQ);
            cwt[tid] = cosf(ang);
            swt[tid] = sinf(ang);
        }

        const int w = tid >> 6;
        const int lane = tid & 63;
        if (w < 3) {
            const int rsel = lane & 15;
            const int koff = (lane >> 4) * 8;
            const int n0 = w * 512 + h * 64;
            f32x4 acc[4][4] = {};
            const bf16_t* Ap = xb + (m0 + rsel) * EMB + koff;
            const bf16_t* Bp = wqb + (n0 + rsel) * EMB + koff;
#pragma unroll 4
            for (int k0 = 0; k0 < EMB; k0 += 32) {
                bf16x8 af[4], bfr[4];
                for (int i = 0; i < 4; ++i)
                    af[i] = *(const bf16x8*)(Ap + i * 16 * EMB + k0);
                for (int j = 0; j < 4; ++j)
                    bfr[j] = *(const bf16x8*)(Bp + j * 16 * EMB + k0);
                for (int i = 0; i < 4; ++i)
                    for (int j = 0; j < 4; ++j)
                        acc[i][j] = __builtin_amdgcn_mfma_f32_16x16x32_bf16(
                            af[i], bfr[j], acc[i][j], 0, 0, 0);
            }
            for (int j = 0; j < 4; ++j) {
                const int feat = j * 16 + rsel;           // 0..63 within head
                const float bn = b_qkv[n0 + feat];
                for (int i = 0; i < 4; ++i) {
                    const int tl0 = i * 16 + (lane >> 4) * 4;
                    for (int r = 0; r < 4; ++r) {
                        const int tl = tl0 + r;
                        const int t = (m0 & 1023) + tl;
                        float val = acc[i][j][r] + bn;
                        int di = ((b * NH + h) * T_SEQ + t) * HD + feat;
                        if (w == 0) {
                            qq[di] = (bf16_t)fmaxf(val, 0.f);
                        } else if (w == 1) {
                            bf16_t kb = (bf16_t)fmaxf(val, 0.f);
                            kk[di] = kb;
                            sk[tl * LDK + feat] = kb;
                        } else {
                            bf16_t vb = (bf16_t)val;
                            vv[di] = vb;
                            sv[tl * LDK + feat] = vb;
                        }
                    }
                }
            }
        }
        __syncthreads();

        // ---- proven chunk_sum body, reading the LDS handoff ----
        const int il = tid & 63;
        const int jg = (tid >> 6) * 16;
        float ac[16], as[16];
        for (int jj = 0; jj < 16; ++jj) { ac[jj] = 0.f; as[jj] = 0.f; }
        float zca = 0.f, zsa = 0.f;
        const bool zown = (jg == 0);
        for (int t = 0; t < CHUNK; ++t) {
            float kv = (float)sk[t * LDK + il];
            float kc_ = kv * cwt[t];
            float ks_ = kv * swt[t];
            if (zown) { zca += kc_; zsa += ks_; }
            for (int jj = 0; jj < 16; ++jj) {
                float vj = (float)sv[t * LDK + jg + jj];
                ac[jj] += kc_ * vj;
                as[jj] += ks_ * vj;
            }
        }
        bf16_t* oc = Ssc + sblk * HD * HD;
        bf16_t* os = Sss + sblk * HD * HD;
        for (int jj = 0; jj < 16; ++jj) {
            oc[(jg + jj) * HD + il] = (bf16_t)ac[jj];   // transposed: [e][i]
            os[(jg + jj) * HD + il] = (bf16_t)as[jj];
        }
        if (zown) {
            zc[sblk * HD + il] = zca;
            zs[sblk * HD + il] = zsa;
        }
    }
    grid.sync();

    // ---------------- phase 2: per-chunk output ----------------------------
    {
        const int bh = blk >> 4, ch = blk & 15;
        bf16_t* sq  = sm.p2.sq;
        bf16_t* skl = sm.p2.sk;
        bf16_t* svT = sm.p2.svT;
        bf16_t* sct = sm.p2.sct;
        bf16_t* sst = sm.p2.sst;
        bf16_t* sp  = sm.p2.sp;
        float* cwt = sm.p2.cwt; float* swt = sm.p2.swt; float* cosd = sm.p2.cosd;
        float* zcl = sm.p2.zcl; float* zsl = sm.p2.zsl; float* nrm = sm.p2.nrm;

        const int base = blk * CHUNK * HD;
        for (int i = tid; i < CHUNK * HD / 8; i += 256) {
            int row = i >> 3, g = i & 7;
            ((uint4*)(sq + row * LDA))[g]  = ((const uint4*)(qq + base))[i];
            ((uint4*)(skl + row * LDA))[g] = ((const uint4*)(kk + base))[i];
            // V transpose with granule rotation (conflict-free; see R12)
            bf16x8 v8 = *(const bf16x8*)(vv + base + i * 8);
            int t = i >> 3, bb = i & 7;
            int tg8 = t >> 3, tf = t & 7;
            for (int j = 0; j < 8; ++j) {
                int e = bb * 8 + j;
                int pg = (tg8 + bb) & 7;
                svT[e * LDA + pg * 8 + tf] = v8[j];
            }
        }
        // on-the-fly exclusive prefix of S over chunks < ch
        {
            const int e0 = tid * 16;
            float accC[16], accS[16];
            for (int j = 0; j < 16; ++j) { accC[j] = 0.f; accS[j] = 0.f; }
            const int sb = bh * NCHUNK * HD * HD + e0;
#pragma unroll 2
            for (int c = 0; c < ch; ++c) {
                const bf16x8* pc = (const bf16x8*)(Ssc + sb + c * HD * HD);
                const bf16x8* ps = (const bf16x8*)(Sss + sb + c * HD * HD);
                bf16x8 c0 = pc[0], c1 = pc[1], s0 = ps[0], s1 = ps[1];
                for (int j = 0; j < 8; ++j) {
                    accC[j] += (float)c0[j];  accC[8 + j] += (float)c1[j];
                    accS[j] += (float)s0[j];  accS[8 + j] += (float)s1[j];
                }
            }
            const int row = tid >> 2, col = (tid & 3) * 16;
            bf16x8 oc0, oc1, os0, os1;
            for (int j = 0; j < 8; ++j) {
                oc0[j] = (bf16_t)accC[j];  oc1[j] = (bf16_t)accC[8 + j];
                os0[j] = (bf16_t)accS[j];  os1[j] = (bf16_t)accS[8 + j];
            }
            *(bf16x8*)(sct + row * LDA + col) = oc0;
            *(bf16x8*)(sct + row * LDA + col + 8) = oc1;
            *(bf16x8*)(sst + row * LDA + col) = os0;
            *(bf16x8*)(sst + row * LDA + col + 8) = os1;
        }
        // z prefix + angle tables
        if (tid < HD) {
            int tl = tid;
            float s = 0.f;
            for (int c = 0; c < ch; ++c) s += zc[(bh * NCHUNK + c) * HD + tl];
            zcl[tl] = s;
            int tg = ch * CHUNK + tl;
            float angg = 1.5707963267948966f * (float)tg * (1.0f / (float)T_SEQ);
            cwt[tl] = cosf(angg);
            swt[tl] = sinf(angg);
            cosd[tl] = cosf(1.5707963267948966f * (float)tl * (1.0f / (float)T_SEQ));
        } else if (tid < 2 * HD) {
            int i = tid - HD;
            float s = 0.f;
            for (int c = 0; c < ch; ++c) s += zs[(bh * NCHUNK + c) * HD + i];
            zsl[i] = s;
        }
        __syncthreads();

        const int w = tid >> 6;
        const int lane = tid & 63;
        const int rsel = lane & 15;
        const int koff = (lane >> 4) * 8;
        const int myrow = w * 16 + rsel;

        // ---- P = q' k'^T, scale+mask, bf16 rows (wave-local) ----
        bf16x8 aq0 = *(const bf16x8*)(sq + myrow * LDA + koff);
        bf16x8 aq1 = *(const bf16x8*)(sq + myrow * LDA + koff + 32);
        for (int nt = 0; nt < 4; ++nt) {
            const int n0 = nt * 16;
            f32x4 pacc = {0.f, 0.f, 0.f, 0.f};
            bf16x8 b0 = *(const bf16x8*)(skl + (n0 + rsel) * LDA + koff);
            bf16x8 b1 = *(const bf16x8*)(skl + (n0 + rsel) * LDA + koff + 32);
            pacc = __builtin_amdgcn_mfma_f32_16x16x32_bf16(aq0, b0, pacc, 0, 0, 0);
            pacc = __builtin_amdgcn_mfma_f32_16x16x32_bf16(aq1, b1, pacc, 0, 0, 0);
            const int s = n0 + (lane & 15);
            const int tb = w * 16 + (lane >> 4) * 4;
            for (int r = 0; r < 4; ++r) {
                int t = tb + r;
                float p = (s <= t) ? pacc[r] * cosd[t - s] : 0.f;
                sp[t * LDA + s] = (bf16_t)p;
            }
        }

        // ---- nrm (lanes 0..15 of each wave; rows wave-local) ----
        if (lane < 16) {
            int row = w * 16 + lane;
            float nv = 0.f;
            const bf16x8* pr = (const bf16x8*)(sp + row * LDA);
            for (int g = 0; g < 8; ++g) {
                bf16x8 pv = pr[g];
                for (int j = 0; j < 8; ++j) nv += (float)pv[j];
            }
            float cwr = cwt[row], swr = swt[row];
            const bf16x8* qr = (const bf16x8*)(sq + row * LDA);
            for (int g = 0; g < 8; ++g) {
                bf16x8 qv = qr[g];
                for (int j = 0; j < 8; ++j)
                    nv += (float)qv[j] * (cwr * zcl[g * 8 + j] + swr * zsl[g * 8 + j]);
            }
            nrm[row] = nv;
        }

        // ---- ctx = P@V + q'c@Sc + q's@Ss ----
        const float cwq = cwt[myrow], swq = swt[myrow];
        bf16x8 qc0, qc1, qs0, qs1;
        for (int j = 0; j < 8; ++j) {
            qc0[j] = (bf16_t)((float)aq0[j] * cwq);
            qc1[j] = (bf16_t)((float)aq1[j] * cwq);
            qs0[j] = (bf16_t)((float)aq0[j] * swq);
            qs1[j] = (bf16_t)((float)aq1[j] * swq);
        }
        bf16x8 ap0 = *(const bf16x8*)(sp + myrow * LDA + koff);
        bf16x8 ap1 = *(const bf16x8*)(sp + myrow * LDA + koff + 32);

        const int b = bh >> 3, h = bh & 7;
        const int g0 = koff >> 3;                       // logical granule 0..3
        for (int nt = 0; nt < 4; ++nt) {
            const int n0 = nt * 16;
            const int ee = n0 + rsel;
            const int rot = (ee >> 3) & 7;
            const bf16_t* bvp0 = svT + ee * LDA + (((g0 + rot) & 7) << 3);
            const bf16_t* bvp1 = svT + ee * LDA + (((g0 + 4 + rot) & 7) << 3);
            const bf16_t* bcp = sct + ee * LDA + koff;
            const bf16_t* bsp = sst + ee * LDA + koff;
            f32x4 acc = {0.f, 0.f, 0.f, 0.f};
            acc = __builtin_amdgcn_mfma_f32_16x16x32_bf16(ap0, *(const bf16x8*)(bvp0), acc, 0, 0, 0);
            acc = __builtin_amdgcn_mfma_f32_16x16x32_bf16(ap1, *(const bf16x8*)(bvp1), acc, 0, 0, 0);
            acc = __builtin_amdgcn_mfma_f32_16x16x32_bf16(qc0, *(const bf16x8*)(bcp), acc, 0, 0, 0);
            acc = __builtin_amdgcn_mfma_f32_16x16x32_bf16(qc1, *(const bf16x8*)(bcp + 32), acc, 0, 0, 0);
            acc = __builtin_amdgcn_mfma_f32_16x16x32_bf16(qs0, *(const bf16x8*)(bsp), acc, 0, 0, 0);
            acc = __builtin_amdgcn_mfma_f32_16x16x32_bf16(qs1, *(const bf16x8*)(bsp + 32), acc, 0, 0, 0);
            const int col = n0 + (lane & 15);
            const int tb = w * 16 + (lane >> 4) * 4;
            for (int r = 0; r < 4; ++r) {
                int row = tb + r;
                float inv = 1.0f / (nrm[row] + 1e-6f);
                int tg = ch * CHUNK + row;
                Y[((b * T_SEQ + tg) * EMB) + h * HD + col] = (bf16_t)(acc[r] * inv);
            }
        }
    }
    grid.sync();

    // ---------------- phase 3: out = Y @ w_out^T + b_out -------------------
    {
        const int w = tid >> 6;
        const int lane = tid & 63;
        const int rsel = lane & 15;
        const int koff = (lane >> 4) * 8;
        const int m0 = (blk & 31) * 64 + (w & 1) * 32;
        const int n0 = (blk >> 5) * 64 + (w >> 1) * 32;
        f32x4 acc[2][2] = {};
        const bf16_t* Ap = Y + (m0 + rsel) * EMB + koff;
        const bf16_t* Bp = wob + (n0 + rsel) * EMB + koff;
#pragma unroll 8
        for (int k0 = 0; k0 < EMB; k0 += 32) {
            bf16x8 af[2], bfr[2];
            for (int i = 0; i < 2; ++i)
                af[i] = *(const bf16x8*)(Ap + i * 16 * EMB + k0);
            for (int j = 0; j < 2; ++j)
                bfr[j] = *(const bf16x8*)(Bp + j * 16 * EMB + k0);
            for (int i = 0; i < 2; ++i)
                for (int j = 0; j < 2; ++j)
                    acc[i][j] = __builtin_amdgcn_mfma_f32_16x16x32_bf16(
                        af[i], bfr[j], acc[i][j], 0, 0, 0);
        }
        for (int j = 0; j < 2; ++j) {
            const int n = n0 + j * 16 + rsel;
            const float bn = b_out[n];
            for (int i = 0; i < 2; ++i) {
                const int mb = m0 + i * 16 + (lane >> 4) * 4;
                for (int r = 0; r < 4; ++r)
                    out[(mb + r) * EMB + n] = acc[i][j][r] + bn;
            }
        }
    }
}

extern "C" void kernel_launch(void* const* d_in, const int* in_sizes, int n_in,
                              void* d_out, int out_size, void* d_ws, size_t ws_size,
                              hipStream_t stream) {
    const float* x     = (const float*)d_in[0];
    const float* w_qkv = (const float*)d_in[1];
    const float* b_qkv = (const float*)d_in[2];
    const float* w_out = (const float*)d_in[3];
    const float* b_out = (const float*)d_in[4];
    float* out = (float*)d_out;

    char* w = (char*)d_ws;
    const size_t N_X   = (size_t)BATCH * T_SEQ * EMB;
    const size_t N_WQ  = (size_t)3 * EMB * EMB;
    const size_t N_WO  = (size_t)EMB * EMB;
    bf16_t* xb   = (bf16_t*)w;                 w += N_X  * sizeof(bf16_t);
    bf16_t* wqb  = (bf16_t*)w;                 w += N_WQ * sizeof(bf16_t);
    bf16_t* wob  = (bf16_t*)w;                 w += N_WO * sizeof(bf16_t);
    const size_t SZ_BHTD = (size_t)NBH * T_SEQ * HD * sizeof(bf16_t);
    bf16_t* qq = (bf16_t*)w;                   w += SZ_BHTD;
    bf16_t* kk = (bf16_t*)w;                   w += SZ_BHTD;
    bf16_t* vv = (bf16_t*)w;                   w += SZ_BHTD;
    bf16_t* Y  = (bf16_t*)w;                   w += SZ_BHTD;
    bf16_t* SscT = (bf16_t*)w;                 w += (size_t)NBLK * HD * HD * sizeof(bf16_t);
    bf16_t* SssT = (bf16_t*)w;                 w += (size_t)NBLK * HD * HD * sizeof(bf16_t);
    float* zc = (float*)w;                     w += (size_t)NBLK * HD * sizeof(float);
    float* zs = (float*)w;

    void* args[] = {
        (void*)&x, (void*)&w_qkv, (void*)&w_out, (void*)&b_qkv, (void*)&b_out,
        (void*)&xb, (void*)&wqb, (void*)&wob,
        (void*)&qq, (void*)&kk, (void*)&vv,
        (void*)&SscT, (void*)&SssT, (void*)&zc, (void*)&zs,
        (void*)&Y, (void*)&out
    };
    hipLaunchCooperativeKernel((const void*)fused_kernel, dim3(NBLK), dim3(256),
                               args, 0, stream);
}

// Round 2
// 139.710 us; speedup vs baseline: 1.5645x; 1.5645x over previous
//
#include <hip/hip_runtime.h>

typedef __bf16 bf16_t;
typedef __bf16 bf16x4 __attribute__((ext_vector_type(4)));
typedef __bf16 bf16x8 __attribute__((ext_vector_type(8)));
typedef float f32x4 __attribute__((ext_vector_type(4)));

#define T_SEQ 1024
#define EMB   512
#define NH    8
#define HD    64
#define BATCH 2
#define NBH   (BATCH*NH)      // 16
#define CHUNK 64
#define NCHUNK (T_SEQ/CHUNK)  // 16
#define NBLK  (NBH*NCHUNK)    // 256
#define LDA   72              // padded LDS row stride (chunk_out)
#define LDK   68              // padded LDS row stride (qkv_sum handoff)

// Identity: with ang_t = (pi/2)*t/T,
//   q_cos[t].k_cos[s] + q_sin[t].k_sin[s] = (q'[t].k'[s]) * cos(ang_t - ang_s)
//
// R14: revert cooperative fusion (grid.sync cost ~120us of stall, measured
// R13). Back to the proven 4-dispatch graph, minus cvt3: both GEMMs now read
// their fp32 operands directly and convert in-register (v_cvt_pk_bf16_f32),
// removing one dispatch + 18 MB of staging traffic. out_gemm split to 512
// blocks (32x64 tiles) for 2 waves/SIMD latency hiding.

__device__ __forceinline__ bf16x8 cvt8(const float* __restrict__ p) {
    float4 a = *(const float4*)p;
    float4 b = *(const float4*)(p + 4);
    bf16x8 r;
    r[0] = (bf16_t)a.x; r[1] = (bf16_t)a.y; r[2] = (bf16_t)a.z; r[3] = (bf16_t)a.w;
    r[4] = (bf16_t)b.x; r[5] = (bf16_t)b.y; r[6] = (bf16_t)b.z; r[7] = (bf16_t)b.w;
    return r;
}

// ---------------------------------------------------------------------------
// K1 (qkv GEMM + chunk_sum): grid (32 m-tiles, 8 heads) = 256 blocks.
// Waves 0/1/2 run the 64x64 one-wave GEMM for q/k/v, reading fp32 x / w_qkv
// and converting to bf16 in-register. k/v epilogues land tiles in LDS;
// after one barrier, all 4 waves run the chunk_sum body from LDS.
// ---------------------------------------------------------------------------
__global__ __launch_bounds__(256) void qkv_sum_kernel(
    const float* __restrict__ X, const float* __restrict__ W,
    const float* __restrict__ bias,
    bf16_t* __restrict__ qq, bf16_t* __restrict__ kk, bf16_t* __restrict__ vv,
    bf16_t* __restrict__ Ssc, bf16_t* __restrict__ Sss,
    float* __restrict__ zc, float* __restrict__ zs)
{
    __shared__ __align__(16) bf16_t sk[CHUNK * LDK];
    __shared__ __align__(16) bf16_t sv[CHUNK * LDK];
    __shared__ float cwt[CHUNK], swt[CHUNK];

    const int m0 = blockIdx.x * 64;
    const int h  = blockIdx.y;
    const int b  = m0 >> 10;
    const int ch = (m0 & 1023) >> 6;
    const int blk = (b * NH + h) * NCHUNK + ch;

    if (threadIdx.x < CHUNK) {
        int tg = ch * CHUNK + threadIdx.x;
        float ang = 1.5707963267948966f * (float)tg * (1.0f / (float)T_SEQ);
        cwt[threadIdx.x] = cosf(ang);
        swt[threadIdx.x] = sinf(ang);
    }

    const int w = threadIdx.x >> 6;
    const int lane = threadIdx.x & 63;
    if (w < 3) {
        const int rsel = lane & 15;
        const int koff = (lane >> 4) * 8;
        const int n0 = w * 512 + h * 64;
        f32x4 acc[4][4] = {};
        const float* Ap = X + (m0 + rsel) * EMB + koff;
        const float* Bp = W + (n0 + rsel) * EMB + koff;
#pragma unroll 2
        for (int k0 = 0; k0 < EMB; k0 += 32) {
            bf16x8 af[4], bfr[4];
            for (int i = 0; i < 4; ++i)
                af[i] = cvt8(Ap + i * 16 * EMB + k0);
            for (int j = 0; j < 4; ++j)
                bfr[j] = cvt8(Bp + j * 16 * EMB + k0);
            for (int i = 0; i < 4; ++i)
                for (int j = 0; j < 4; ++j)
                    acc[i][j] = __builtin_amdgcn_mfma_f32_16x16x32_bf16(
                        af[i], bfr[j], acc[i][j], 0, 0, 0);
        }
        for (int j = 0; j < 4; ++j) {
            const int feat = j * 16 + rsel;           // 0..63 within head
            const float bn = bias[n0 + feat];
            for (int i = 0; i < 4; ++i) {
                const int tl0 = i * 16 + (lane >> 4) * 4;   // local t, 4-aligned
                for (int r = 0; r < 4; ++r) {
                    const int tl = tl0 + r;
                    const int t = (m0 & 1023) + tl;
                    float val = acc[i][j][r] + bn;
                    int di = ((b * NH + h) * T_SEQ + t) * HD + feat;
                    if (w == 0) {
                        qq[di] = (bf16_t)fmaxf(val, 0.f);
                    } else if (w == 1) {
                        bf16_t kb = (bf16_t)fmaxf(val, 0.f);
                        kk[di] = kb;
                        sk[tl * LDK + feat] = kb;
                    } else {
                        bf16_t vb = (bf16_t)val;
                        vv[di] = vb;
                        sv[tl * LDK + feat] = vb;
                    }
                }
            }
        }
    }
    __syncthreads();

    // ---- proven chunk_sum body, reading the LDS handoff (stride LDK) ----
    const int i  = threadIdx.x & 63;
    const int jg = (threadIdx.x >> 6) * 16;
    float ac[16], as[16];
    for (int jj = 0; jj < 16; ++jj) { ac[jj] = 0.f; as[jj] = 0.f; }
    float zca = 0.f, zsa = 0.f;
    const bool zown = (jg == 0);
    for (int t = 0; t < CHUNK; ++t) {
        float kv = (float)sk[t * LDK + i];
        float kc_ = kv * cwt[t];
        float ks_ = kv * swt[t];
        if (zown) { zca += kc_; zsa += ks_; }
        for (int jj = 0; jj < 16; ++jj) {
            float vj = (float)sv[t * LDK + jg + jj];
            ac[jj] += kc_ * vj;
            as[jj] += ks_ * vj;
        }
    }
    bf16_t* oc = Ssc + blk * HD * HD;
    bf16_t* os = Sss + blk * HD * HD;
    for (int jj = 0; jj < 16; ++jj) {
        oc[(jg + jj) * HD + i] = (bf16_t)ac[jj];   // transposed: [e][i]
        os[(jg + jj) * HD + i] = (bf16_t)as[jj];
    }
    if (zown) {
        zc[blk * HD + i] = zca;
        zs[blk * HD + i] = zsa;
    }
}

// ---------------------------------------------------------------------------
// K2: per-chunk output with on-the-fly S/z prefix (unroll-2 prefix loop)
// and the R12 bank-swizzled svT (granule rotation rot(e)=e>>3).
// ---------------------------------------------------------------------------
__global__ __launch_bounds__(256) void chunk_out_kernel(
    const bf16_t* __restrict__ qq, const bf16_t* __restrict__ kk,
    const bf16_t* __restrict__ vv,
    const bf16_t* __restrict__ SscT, const bf16_t* __restrict__ SssT,
    const float* __restrict__ zc, const float* __restrict__ zs,
    bf16_t* __restrict__ Y)
{
    const int blk = blockIdx.x;
    const int bh = blk >> 4, ch = blk & 15;
    __shared__ __align__(16) bf16_t sq [CHUNK * LDA];
    __shared__ __align__(16) bf16_t sk [CHUNK * LDA];
    __shared__ __align__(16) bf16_t svT[CHUNK * LDA];
    __shared__ __align__(16) bf16_t sct[CHUNK * LDA];
    __shared__ __align__(16) bf16_t sst[CHUNK * LDA];
    __shared__ __align__(16) bf16_t sp [CHUNK * LDA];
    __shared__ float cwt[CHUNK], swt[CHUNK], cosd[CHUNK];
    __shared__ float zcl[CHUNK], zsl[CHUNK], nrm[CHUNK];

    const int base = blk * CHUNK * HD;
    for (int i = threadIdx.x; i < CHUNK * HD / 8; i += 256) {
        int row = i >> 3, g = i & 7;
        ((uint4*)(sq + row * LDA))[g]  = ((const uint4*)(qq + base))[i];
        ((uint4*)(sk + row * LDA))[g]  = ((const uint4*)(kk + base))[i];
        // V transpose with granule rotation (conflict-free; see R12)
        bf16x8 v8 = *(const bf16x8*)(vv + base + i * 8);
        int t = i >> 3, bb = i & 7;
        int tg8 = t >> 3, tf = t & 7;
        for (int j = 0; j < 8; ++j) {
            int e = bb * 8 + j;
            int pg = (tg8 + bb) & 7;
            svT[e * LDA + pg * 8 + tf] = v8[j];
        }
    }
    // on-the-fly exclusive prefix of S over chunks < ch (fp32 acc -> bf16 LDS)
    {
        const int e0 = threadIdx.x * 16;            // flat elems [e0, e0+16)
        float accC[16], accS[16];
        for (int j = 0; j < 16; ++j) { accC[j] = 0.f; accS[j] = 0.f; }
        const int sb = bh * NCHUNK * HD * HD + e0;
#pragma unroll 2
        for (int c = 0; c < ch; ++c) {
            const bf16x8* pc = (const bf16x8*)(SscT + sb + c * HD * HD);
            const bf16x8* ps = (const bf16x8*)(SssT + sb + c * HD * HD);
            bf16x8 c0 = pc[0], c1 = pc[1], s0 = ps[0], s1 = ps[1];
            for (int j = 0; j < 8; ++j) {
                accC[j] += (float)c0[j];  accC[8 + j] += (float)c1[j];
                accS[j] += (float)s0[j];  accS[8 + j] += (float)s1[j];
            }
        }
        const int row = threadIdx.x >> 2, col = (threadIdx.x & 3) * 16;
        bf16x8 oc0, oc1, os0, os1;
        for (int j = 0; j < 8; ++j) {
            oc0[j] = (bf16_t)accC[j];  oc1[j] = (bf16_t)accC[8 + j];
            os0[j] = (bf16_t)accS[j];  os1[j] = (bf16_t)accS[8 + j];
        }
        *(bf16x8*)(sct + row * LDA + col) = oc0;
        *(bf16x8*)(sct + row * LDA + col + 8) = oc1;
        *(bf16x8*)(sst + row * LDA + col) = os0;
        *(bf16x8*)(sst + row * LDA + col + 8) = os1;
    }
    // z prefix + angle tables
    if (threadIdx.x < HD) {
        int tl = threadIdx.x;
        float s = 0.f;
        for (int c = 0; c < ch; ++c) s += zc[(bh * NCHUNK + c) * HD + tl];
        zcl[tl] = s;
        int tg = ch * CHUNK + tl;
        float angg = 1.5707963267948966f * (float)tg * (1.0f / (float)T_SEQ);
        cwt[tl] = cosf(angg);
        swt[tl] = sinf(angg);
        cosd[tl] = cosf(1.5707963267948966f * (float)tl * (1.0f / (float)T_SEQ));
    } else if (threadIdx.x < 2 * HD) {
        int i = threadIdx.x - HD;
        float s = 0.f;
        for (int c = 0; c < ch; ++c) s += zs[(bh * NCHUNK + c) * HD + i];
        zsl[i] = s;
    }
    __syncthreads();

    const int w = threadIdx.x >> 6;
    const int lane = threadIdx.x & 63;
    const int rsel = lane & 15;
    const int koff = (lane >> 4) * 8;
    const int myrow = w * 16 + rsel;

    // ---- P = q' k'^T, scale+mask, bf16 rows (wave-local) ----
    bf16x8 aq0 = *(const bf16x8*)(sq + myrow * LDA + koff);
    bf16x8 aq1 = *(const bf16x8*)(sq + myrow * LDA + koff + 32);
    for (int nt = 0; nt < 4; ++nt) {
        const int n0 = nt * 16;
        f32x4 pacc = {0.f, 0.f, 0.f, 0.f};
        bf16x8 b0 = *(const bf16x8*)(sk + (n0 + rsel) * LDA + koff);
        bf16x8 b1 = *(const bf16x8*)(sk + (n0 + rsel) * LDA + koff + 32);
        pacc = __builtin_amdgcn_mfma_f32_16x16x32_bf16(aq0, b0, pacc, 0, 0, 0);
        pacc = __builtin_amdgcn_mfma_f32_16x16x32_bf16(aq1, b1, pacc, 0, 0, 0);
        const int s = n0 + (lane & 15);
        const int tb = w * 16 + (lane >> 4) * 4;
        for (int r = 0; r < 4; ++r) {
            int t = tb + r;
            float p = (s <= t) ? pacc[r] * cosd[t - s] : 0.f;
            sp[t * LDA + s] = (bf16_t)p;
        }
    }

    // ---- nrm (lanes 0..15 of each wave; rows wave-local) ----
    if (lane < 16) {
        int row = w * 16 + lane;
        float nv = 0.f;
        const bf16x8* pr = (const bf16x8*)(sp + row * LDA);
        for (int g = 0; g < 8; ++g) {
            bf16x8 pv = pr[g];
            for (int j = 0; j < 8; ++j) nv += (float)pv[j];
        }
        float cwr = cwt[row], swr = swt[row];
        const bf16x8* qr = (const bf16x8*)(sq + row * LDA);
        for (int g = 0; g < 8; ++g) {
            bf16x8 qv = qr[g];
            for (int j = 0; j < 8; ++j)
                nv += (float)qv[j] * (cwr * zcl[g * 8 + j] + swr * zsl[g * 8 + j]);
        }
        nrm[row] = nv;
    }

    // ---- ctx = P@V + q'c@Sc + q's@Ss ----
    const float cwq = cwt[myrow], swq = swt[myrow];
    bf16x8 qc0, qc1, qs0, qs1;
    for (int j = 0; j < 8; ++j) {
        qc0[j] = (bf16_t)((float)aq0[j] * cwq);
        qc1[j] = (bf16_t)((float)aq1[j] * cwq);
        qs0[j] = (bf16_t)((float)aq0[j] * swq);
        qs1[j] = (bf16_t)((float)aq1[j] * swq);
    }
    bf16x8 ap0 = *(const bf16x8*)(sp + myrow * LDA + koff);
    bf16x8 ap1 = *(const bf16x8*)(sp + myrow * LDA + koff + 32);

    const int b = bh >> 3, h = bh & 7;
    const int g0 = koff >> 3;                       // logical granule 0..3
    for (int nt = 0; nt < 4; ++nt) {
        const int n0 = nt * 16;
        const int ee = n0 + rsel;
        const int rot = (ee >> 3) & 7;
        const bf16_t* bvp0 = svT + ee * LDA + (((g0 + rot) & 7) << 3);
        const bf16_t* bvp1 = svT + ee * LDA + (((g0 + 4 + rot) & 7) << 3);
        const bf16_t* bcp = sct + ee * LDA + koff;
        const bf16_t* bsp = sst + ee * LDA + koff;
        f32x4 acc = {0.f, 0.f, 0.f, 0.f};
        acc = __builtin_amdgcn_mfma_f32_16x16x32_bf16(ap0, *(const bf16x8*)(bvp0), acc, 0, 0, 0);
        acc = __builtin_amdgcn_mfma_f32_16x16x32_bf16(ap1, *(const bf16x8*)(bvp1), acc, 0, 0, 0);
        acc = __builtin_amdgcn_mfma_f32_16x16x32_bf16(qc0, *(const bf16x8*)(bcp), acc, 0, 0, 0);
        acc = __builtin_amdgcn_mfma_f32_16x16x32_bf16(qc1, *(const bf16x8*)(bcp + 32), acc, 0, 0, 0);
        acc = __builtin_amdgcn_mfma_f32_16x16x32_bf16(qs0, *(const bf16x8*)(bsp), acc, 0, 0, 0);
        acc = __builtin_amdgcn_mfma_f32_16x16x32_bf16(qs1, *(const bf16x8*)(bsp + 32), acc, 0, 0, 0);
        const int col = n0 + (lane & 15);
        const int tb = w * 16 + (lane >> 4) * 4;
        for (int r = 0; r < 4; ++r) {
            int row = tb + r;
            float inv = 1.0f / (nrm[row] + 1e-6f);
            int tg = ch * CHUNK + row;
            Y[((b * T_SEQ + tg) * EMB) + h * HD + col] = (bf16_t)(acc[r] * inv);
        }
    }
}

// ---------------------------------------------------------------------------
// K3: out = Y @ w_out^T + b_out. 512 blocks (32x64 tile), 2 blocks/CU for
// latency hiding; w_out read as fp32 and converted in-register.
// ---------------------------------------------------------------------------
__global__ __launch_bounds__(256) void out_gemm_kernel(
    const bf16_t* __restrict__ Yb, const float* __restrict__ W,
    const float* __restrict__ bias, float* __restrict__ out)
{
    const int w = threadIdx.x >> 6;
    const int lane = threadIdx.x & 63;
    const int rsel = lane & 15;
    const int koff = (lane >> 4) * 8;
    const int m0 = blockIdx.x * 32 + (w & 1) * 16;
    const int n0 = blockIdx.y * 64 + (w >> 1) * 32;
    f32x4 acc[2] = {};
    const bf16_t* Ap = Yb + (m0 + rsel) * EMB + koff;
    const float* Bp = W + (n0 + rsel) * EMB + koff;
#pragma unroll 4
    for (int k0 = 0; k0 < EMB; k0 += 32) {
        bf16x8 af = *(const bf16x8*)(Ap + k0);
        bf16x8 bfr[2];
        for (int j = 0; j < 2; ++j)
            bfr[j] = cvt8(Bp + j * 16 * EMB + k0);
        for (int j = 0; j < 2; ++j)
            acc[j] = __builtin_amdgcn_mfma_f32_16x16x32_bf16(
                af, bfr[j], acc[j], 0, 0, 0);
    }
    for (int j = 0; j < 2; ++j) {
        const int n = n0 + j * 16 + rsel;
        const float bn = bias[n];
        const int mb = m0 + (lane >> 4) * 4;
        for (int r = 0; r < 4; ++r)
            out[(mb + r) * EMB + n] = acc[j][r] + bn;
    }
}

extern "C" void kernel_launch(void* const* d_in, const int* in_sizes, int n_in,
                              void* d_out, int out_size, void* d_ws, size_t ws_size,
                              hipStream_t stream) {
    const float* x     = (const float*)d_in[0];
    const float* w_qkv = (const float*)d_in[1];
    const float* b_qkv = (const float*)d_in[2];
    const float* w_out = (const float*)d_in[3];
    const float* b_out = (const float*)d_in[4];
    float* out = (float*)d_out;

    char* w = (char*)d_ws;
    const size_t SZ_BHTD = (size_t)NBH * T_SEQ * HD * sizeof(bf16_t);
    bf16_t* qq = (bf16_t*)w;                   w += SZ_BHTD;
    bf16_t* kk = (bf16_t*)w;                   w += SZ_BHTD;
    bf16_t* vv = (bf16_t*)w;                   w += SZ_BHTD;
    bf16_t* Y  = (bf16_t*)w;                   w += SZ_BHTD;
    bf16_t* SscT = (bf16_t*)w;                 w += (size_t)NBLK * HD * HD * sizeof(bf16_t);
    bf16_t* SssT = (bf16_t*)w;                 w += (size_t)NBLK * HD * HD * sizeof(bf16_t);
    float* zc = (float*)w;                     w += (size_t)NBLK * HD * sizeof(float);
    float* zs = (float*)w;

    qkv_sum_kernel<<<dim3(32, 8), 256, 0, stream>>>(
        x, w_qkv, b_qkv, qq, kk, vv, SscT, SssT, zc, zs);
    chunk_out_kernel<<<NBLK, 256, 0, stream>>>(qq, kk, vv, SscT, SssT, zc, zs, Y);
    out_gemm_kernel<<<dim3(2048 / 32, 512 / 64), 256, 0, stream>>>(
        Y, w_out, b_out, out);
}

// Round 4
// 129.760 us; speedup vs baseline: 1.6845x; 1.0767x over previous
//
#include <hip/hip_runtime.h>

typedef __bf16 bf16_t;
typedef __bf16 bf16x4 __attribute__((ext_vector_type(4)));
typedef __bf16 bf16x8 __attribute__((ext_vector_type(8)));
typedef float f32x4 __attribute__((ext_vector_type(4)));

#define T_SEQ 1024
#define EMB   512
#define NH    8
#define HD    64
#define BATCH 2
#define NBH   (BATCH*NH)      // 16
#define CHUNK 64
#define NCHUNK (T_SEQ/CHUNK)  // 16
#define NBLK  (NBH*NCHUNK)    // 256
#define LDA   72              // padded LDS row stride (chunk_out)
#define LDK   68              // padded LDS row stride (qkv_sum handoff)

// Identity: with ang_t = (pi/2)*t/T,
//   q_cos[t].k_cos[s] + q_sin[t].k_sin[s] = (q'[t].k'[s]) * cos(ang_t - ang_s)
//
// R16 = R15 with the out_gemm launch arg fixed (wob, not w_out).
// R15: qkv k-loop is global-load LATENCY bound (R2 evidence: fp32 in-loop
// reads 2.9x'd the kernel; MfmaUtil 2.2%). Fix = wave concurrency, not bytes:
// qkv_sum now runs 1024 threads/block -> 12 GEMM waves (4 m-quarters x 3
// q/k/v) of 16x64 tiles = 3 GEMM waves/SIMD (was 1). bf16 staging via cvt3
// restored (proven). out_gemm keeps the 512-block split on bf16 W.

// ---------------------------------------------------------------------------
// K0: fused fp32 -> bf16 convert for x, w_qkv, w_out (one dispatch).
// ---------------------------------------------------------------------------
__global__ __launch_bounds__(256) void cvt3_kernel(
    const float* __restrict__ x, const float* __restrict__ wq,
    const float* __restrict__ wo,
    bf16_t* __restrict__ xb, bf16_t* __restrict__ wqb, bf16_t* __restrict__ wob)
{
    int i = blockIdx.x * 256 + threadIdx.x;
    const float* s; bf16_t* d; int off;
    if (i < 262144)      { s = x;  d = xb;  off = i; }
    else if (i < 458752) { s = wq; d = wqb; off = i - 262144; }
    else                 { s = wo; d = wob; off = i - 458752; }
    float4 v = ((const float4*)s)[off];
    bf16x4 o;
    o[0] = (bf16_t)v.x; o[1] = (bf16_t)v.y;
    o[2] = (bf16_t)v.z; o[3] = (bf16_t)v.w;
    ((bf16x4*)d)[off] = o;
}

// ---------------------------------------------------------------------------
// K1 (qkv GEMM + chunk_sum): grid (32 m-tiles, 8 heads) = 256 blocks of
// 1024 threads. Waves 0..11: 16x64 GEMM tiles (mh = ww&3 m-quarter,
// sel = ww>>2 in {q,k,v}). k/v epilogues land tiles in LDS (stride LDK);
// after one barrier all 16 waves run chunk_sum (4 v-cols per wave).
// ---------------------------------------------------------------------------
__global__ __launch_bounds__(1024) void qkv_sum_kernel(
    const bf16_t* __restrict__ X, const bf16_t* __restrict__ W,
    const float* __restrict__ bias,
    bf16_t* __restrict__ qq, bf16_t* __restrict__ kk, bf16_t* __restrict__ vv,
    bf16_t* __restrict__ Ssc, bf16_t* __restrict__ Sss,
    float* __restrict__ zc, float* __restrict__ zs)
{
    __shared__ __align__(16) bf16_t sk[CHUNK * LDK];
    __shared__ __align__(16) bf16_t sv[CHUNK * LDK];
    __shared__ float cwt[CHUNK], swt[CHUNK];

    const int m0 = blockIdx.x * 64;
    const int h  = blockIdx.y;
    const int b  = m0 >> 10;
    const int ch = (m0 & 1023) >> 6;
    const int blk = (b * NH + h) * NCHUNK + ch;

    if (threadIdx.x < CHUNK) {
        int tg = ch * CHUNK + threadIdx.x;
        float ang = 1.5707963267948966f * (float)tg * (1.0f / (float)T_SEQ);
        cwt[threadIdx.x] = cosf(ang);
        swt[threadIdx.x] = sinf(ang);
    }

    const int ww = threadIdx.x >> 6;
    const int lane = threadIdx.x & 63;
    if (ww < 12) {
        const int mh  = ww & 3;             // m-quarter: rows mh*16..mh*16+15
        const int sel = ww >> 2;            // 0=q 1=k 2=v
        const int rsel = lane & 15;
        const int koff = (lane >> 4) * 8;
        const int n0 = sel * 512 + h * 64;
        f32x4 acc[4] = {};
        const bf16_t* Ap = X + (m0 + mh * 16 + rsel) * EMB + koff;
        const bf16_t* Bp = W + (n0 + rsel) * EMB + koff;
#pragma unroll 4
        for (int k0 = 0; k0 < EMB; k0 += 32) {
            bf16x8 af = *(const bf16x8*)(Ap + k0);
            bf16x8 bfr[4];
            for (int j = 0; j < 4; ++j)
                bfr[j] = *(const bf16x8*)(Bp + j * 16 * EMB + k0);
            for (int j = 0; j < 4; ++j)
                acc[j] = __builtin_amdgcn_mfma_f32_16x16x32_bf16(
                    af, bfr[j], acc[j], 0, 0, 0);
        }
        for (int j = 0; j < 4; ++j) {
            const int feat = j * 16 + rsel;           // 0..63 within head
            const float bn = bias[n0 + feat];
            const int tl0 = mh * 16 + (lane >> 4) * 4;  // local t, 4-aligned
            for (int r = 0; r < 4; ++r) {
                const int tl = tl0 + r;
                const int t = (m0 & 1023) + tl;
                float val = acc[j][r] + bn;
                int di = ((b * NH + h) * T_SEQ + t) * HD + feat;
                if (sel == 0) {
                    qq[di] = (bf16_t)fmaxf(val, 0.f);
                } else if (sel == 1) {
                    bf16_t kb = (bf16_t)fmaxf(val, 0.f);
                    kk[di] = kb;
                    sk[tl * LDK + feat] = kb;
                } else {
                    bf16_t vb = (bf16_t)val;
                    vv[di] = vb;
                    sv[tl * LDK + feat] = vb;
                }
            }
        }
    }
    __syncthreads();

    // ---- chunk_sum body from LDS handoff: 16 waves x 4 v-cols each ----
    const int i  = lane;
    const int jg = ww * 4;
    float ac[4], as[4];
    for (int jj = 0; jj < 4; ++jj) { ac[jj] = 0.f; as[jj] = 0.f; }
    float zca = 0.f, zsa = 0.f;
    const bool zown = (jg == 0);
    for (int t = 0; t < CHUNK; ++t) {
        float kv = (float)sk[t * LDK + i];
        float kc_ = kv * cwt[t];
        float ks_ = kv * swt[t];
        if (zown) { zca += kc_; zsa += ks_; }
        for (int jj = 0; jj < 4; ++jj) {
            float vj = (float)sv[t * LDK + jg + jj];
            ac[jj] += kc_ * vj;
            as[jj] += ks_ * vj;
        }
    }
    bf16_t* oc = Ssc + blk * HD * HD;
    bf16_t* os = Sss + blk * HD * HD;
    for (int jj = 0; jj < 4; ++jj) {
        oc[(jg + jj) * HD + i] = (bf16_t)ac[jj];   // transposed: [e][i]
        os[(jg + jj) * HD + i] = (bf16_t)as[jj];
    }
    if (zown) {
        zc[blk * HD + i] = zca;
        zs[blk * HD + i] = zsa;
    }
}

// ---------------------------------------------------------------------------
// K2: per-chunk output with on-the-fly S/z prefix (unroll-2 prefix loop)
// and the R12 bank-swizzled svT (granule rotation rot(e)=e>>3).
// ---------------------------------------------------------------------------
__global__ __launch_bounds__(256) void chunk_out_kernel(
    const bf16_t* __restrict__ qq, const bf16_t* __restrict__ kk,
    const bf16_t* __restrict__ vv,
    const bf16_t* __restrict__ SscT, const bf16_t* __restrict__ SssT,
    const float* __restrict__ zc, const float* __restrict__ zs,
    bf16_t* __restrict__ Y)
{
    const int blk = blockIdx.x;
    const int bh = blk >> 4, ch = blk & 15;
    __shared__ __align__(16) bf16_t sq [CHUNK * LDA];
    __shared__ __align__(16) bf16_t sk [CHUNK * LDA];
    __shared__ __align__(16) bf16_t svT[CHUNK * LDA];
    __shared__ __align__(16) bf16_t sct[CHUNK * LDA];
    __shared__ __align__(16) bf16_t sst[CHUNK * LDA];
    __shared__ __align__(16) bf16_t sp [CHUNK * LDA];
    __shared__ float cwt[CHUNK], swt[CHUNK], cosd[CHUNK];
    __shared__ float zcl[CHUNK], zsl[CHUNK], nrm[CHUNK];

    const int base = blk * CHUNK * HD;
    for (int i = threadIdx.x; i < CHUNK * HD / 8; i += 256) {
        int row = i >> 3, g = i & 7;
        ((uint4*)(sq + row * LDA))[g]  = ((const uint4*)(qq + base))[i];
        ((uint4*)(sk + row * LDA))[g]  = ((const uint4*)(kk + base))[i];
        // V transpose with granule rotation (conflict-free; see R12)
        bf16x8 v8 = *(const bf16x8*)(vv + base + i * 8);
        int t = i >> 3, bb = i & 7;
        int tg8 = t >> 3, tf = t & 7;
        for (int j = 0; j < 8; ++j) {
            int e = bb * 8 + j;
            int pg = (tg8 + bb) & 7;
            svT[e * LDA + pg * 8 + tf] = v8[j];
        }
    }
    // on-the-fly exclusive prefix of S over chunks < ch (fp32 acc -> bf16 LDS)
    {
        const int e0 = threadIdx.x * 16;            // flat elems [e0, e0+16)
        float accC[16], accS[16];
        for (int j = 0; j < 16; ++j) { accC[j] = 0.f; accS[j] = 0.f; }
        const int sb = bh * NCHUNK * HD * HD + e0;
#pragma unroll 2
        for (int c = 0; c < ch; ++c) {
            const bf16x8* pc = (const bf16x8*)(SscT + sb + c * HD * HD);
            const bf16x8* ps = (const bf16x8*)(SssT + sb + c * HD * HD);
            bf16x8 c0 = pc[0], c1 = pc[1], s0 = ps[0], s1 = ps[1];
            for (int j = 0; j < 8; ++j) {
                accC[j] += (float)c0[j];  accC[8 + j] += (float)c1[j];
                accS[j] += (float)s0[j];  accS[8 + j] += (float)s1[j];
            }
        }
        const int row = threadIdx.x >> 2, col = (threadIdx.x & 3) * 16;
        bf16x8 oc0, oc1, os0, os1;
        for (int j = 0; j < 8; ++j) {
            oc0[j] = (bf16_t)accC[j];  oc1[j] = (bf16_t)accC[8 + j];
            os0[j] = (bf16_t)accS[j];  os1[j] = (bf16_t)accS[8 + j];
        }
        *(bf16x8*)(sct + row * LDA + col) = oc0;
        *(bf16x8*)(sct + row * LDA + col + 8) = oc1;
        *(bf16x8*)(sst + row * LDA + col) = os0;
        *(bf16x8*)(sst + row * LDA + col + 8) = os1;
    }
    // z prefix + angle tables
    if (threadIdx.x < HD) {
        int tl = threadIdx.x;
        float s = 0.f;
        for (int c = 0; c < ch; ++c) s += zc[(bh * NCHUNK + c) * HD + tl];
        zcl[tl] = s;
        int tg = ch * CHUNK + tl;
        float angg = 1.5707963267948966f * (float)tg * (1.0f / (float)T_SEQ);
        cwt[tl] = cosf(angg);
        swt[tl] = sinf(angg);
        cosd[tl] = cosf(1.5707963267948966f * (float)tl * (1.0f / (float)T_SEQ));
    } else if (threadIdx.x < 2 * HD) {
        int i = threadIdx.x - HD;
        float s = 0.f;
        for (int c = 0; c < ch; ++c) s += zs[(bh * NCHUNK + c) * HD + i];
        zsl[i] = s;
    }
    __syncthreads();

    const int w = threadIdx.x >> 6;
    const int lane = threadIdx.x & 63;
    const int rsel = lane & 15;
    const int koff = (lane >> 4) * 8;
    const int myrow = w * 16 + rsel;

    // ---- P = q' k'^T, scale+mask, bf16 rows (wave-local) ----
    bf16x8 aq0 = *(const bf16x8*)(sq + myrow * LDA + koff);
    bf16x8 aq1 = *(const bf16x8*)(sq + myrow * LDA + koff + 32);
    for (int nt = 0; nt < 4; ++nt) {
        const int n0 = nt * 16;
        f32x4 pacc = {0.f, 0.f, 0.f, 0.f};
        bf16x8 b0 = *(const bf16x8*)(sk + (n0 + rsel) * LDA + koff);
        bf16x8 b1 = *(const bf16x8*)(sk + (n0 + rsel) * LDA + koff + 32);
        pacc = __builtin_amdgcn_mfma_f32_16x16x32_bf16(aq0, b0, pacc, 0, 0, 0);
        pacc = __builtin_amdgcn_mfma_f32_16x16x32_bf16(aq1, b1, pacc, 0, 0, 0);
        const int s = n0 + (lane & 15);
        const int tb = w * 16 + (lane >> 4) * 4;
        for (int r = 0; r < 4; ++r) {
            int t = tb + r;
            float p = (s <= t) ? pacc[r] * cosd[t - s] : 0.f;
            sp[t * LDA + s] = (bf16_t)p;
        }
    }

    // ---- nrm (lanes 0..15 of each wave; rows wave-local) ----
    if (lane < 16) {
        int row = w * 16 + lane;
        float nv = 0.f;
        const bf16x8* pr = (const bf16x8*)(sp + row * LDA);
        for (int g = 0; g < 8; ++g) {
            bf16x8 pv = pr[g];
            for (int j = 0; j < 8; ++j) nv += (float)pv[j];
        }
        float cwr = cwt[row], swr = swt[row];
        const bf16x8* qr = (const bf16x8*)(sq + row * LDA);
        for (int g = 0; g < 8; ++g) {
            bf16x8 qv = qr[g];
            for (int j = 0; j < 8; ++j)
                nv += (float)qv[j] * (cwr * zcl[g * 8 + j] + swr * zsl[g * 8 + j]);
        }
        nrm[row] = nv;
    }

    // ---- ctx = P@V + q'c@Sc + q's@Ss ----
    const float cwq = cwt[myrow], swq = swt[myrow];
    bf16x8 qc0, qc1, qs0, qs1;
    for (int j = 0; j < 8; ++j) {
        qc0[j] = (bf16_t)((float)aq0[j] * cwq);
        qc1[j] = (bf16_t)((float)aq1[j] * cwq);
        qs0[j] = (bf16_t)((float)aq0[j] * swq);
        qs1[j] = (bf16_t)((float)aq1[j] * swq);
    }
    bf16x8 ap0 = *(const bf16x8*)(sp + myrow * LDA + koff);
    bf16x8 ap1 = *(const bf16x8*)(sp + myrow * LDA + koff + 32);

    const int b = bh >> 3, h = bh & 7;
    const int g0 = koff >> 3;                       // logical granule 0..3
    for (int nt = 0; nt < 4; ++nt) {
        const int n0 = nt * 16;
        const int ee = n0 + rsel;
        const int rot = (ee >> 3) & 7;
        const bf16_t* bvp0 = svT + ee * LDA + (((g0 + rot) & 7) << 3);
        const bf16_t* bvp1 = svT + ee * LDA + (((g0 + 4 + rot) & 7) << 3);
        const bf16_t* bcp = sct + ee * LDA + koff;
        const bf16_t* bsp = sst + ee * LDA + koff;
        f32x4 acc = {0.f, 0.f, 0.f, 0.f};
        acc = __builtin_amdgcn_mfma_f32_16x16x32_bf16(ap0, *(const bf16x8*)(bvp0), acc, 0, 0, 0);
        acc = __builtin_amdgcn_mfma_f32_16x16x32_bf16(ap1, *(const bf16x8*)(bvp1), acc, 0, 0, 0);
        acc = __builtin_amdgcn_mfma_f32_16x16x32_bf16(qc0, *(const bf16x8*)(bcp), acc, 0, 0, 0);
        acc = __builtin_amdgcn_mfma_f32_16x16x32_bf16(qc1, *(const bf16x8*)(bcp + 32), acc, 0, 0, 0);
        acc = __builtin_amdgcn_mfma_f32_16x16x32_bf16(qs0, *(const bf16x8*)(bsp), acc, 0, 0, 0);
        acc = __builtin_amdgcn_mfma_f32_16x16x32_bf16(qs1, *(const bf16x8*)(bsp + 32), acc, 0, 0, 0);
        const int col = n0 + (lane & 15);
        const int tb = w * 16 + (lane >> 4) * 4;
        for (int r = 0; r < 4; ++r) {
            int row = tb + r;
            float inv = 1.0f / (nrm[row] + 1e-6f);
            int tg = ch * CHUNK + row;
            Y[((b * T_SEQ + tg) * EMB) + h * HD + col] = (bf16_t)(acc[r] * inv);
        }
    }
}

// ---------------------------------------------------------------------------
// K3: out = Y @ w_out^T + b_out. 512 blocks (32x64 tile) = 2 blocks/CU;
// 4 waves of 16x32 each, bf16 operands, fp32 out.
// ---------------------------------------------------------------------------
__global__ __launch_bounds__(256) void out_gemm_kernel(
    const bf16_t* __restrict__ Yb, const bf16_t* __restrict__ W,
    const float* __restrict__ bias, float* __restrict__ out)
{
    const int w = threadIdx.x >> 6;
    const int lane = threadIdx.x & 63;
    const int rsel = lane & 15;
    const int koff = (lane >> 4) * 8;
    const int m0 = blockIdx.x * 32 + (w & 1) * 16;
    const int n0 = blockIdx.y * 64 + (w >> 1) * 32;
    f32x4 acc[2] = {};
    const bf16_t* Ap = Yb + (m0 + rsel) * EMB + koff;
    const bf16_t* Bp = W + (n0 + rsel) * EMB + koff;
#pragma unroll 4
    for (int k0 = 0; k0 < EMB; k0 += 32) {
        bf16x8 af = *(const bf16x8*)(Ap + k0);
        bf16x8 bfr[2];
        for (int j = 0; j < 2; ++j)
            bfr[j] = *(const bf16x8*)(Bp + j * 16 * EMB + k0);
        for (int j = 0; j < 2; ++j)
            acc[j] = __builtin_amdgcn_mfma_f32_16x16x32_bf16(
                af, bfr[j], acc[j], 0, 0, 0);
    }
    for (int j = 0; j < 2; ++j) {
        const int n = n0 + j * 16 + rsel;
        const float bn = bias[n];
        const int mb = m0 + (lane >> 4) * 4;
        for (int r = 0; r < 4; ++r)
            out[(mb + r) * EMB + n] = acc[j][r] + bn;
    }
}

extern "C" void kernel_launch(void* const* d_in, const int* in_sizes, int n_in,
                              void* d_out, int out_size, void* d_ws, size_t ws_size,
                              hipStream_t stream) {
    const float* x     = (const float*)d_in[0];
    const float* w_qkv = (const float*)d_in[1];
    const float* b_qkv = (const float*)d_in[2];
    const float* w_out = (const float*)d_in[3];
    const float* b_out = (const float*)d_in[4];
    float* out = (float*)d_out;

    char* w = (char*)d_ws;
    const size_t N_X   = (size_t)BATCH * T_SEQ * EMB;
    const size_t N_WQ  = (size_t)3 * EMB * EMB;
    const size_t N_WO  = (size_t)EMB * EMB;
    bf16_t* xb   = (bf16_t*)w;                 w += N_X  * sizeof(bf16_t);
    bf16_t* wqb  = (bf16_t*)w;                 w += N_WQ * sizeof(bf16_t);
    bf16_t* wob  = (bf16_t*)w;                 w += N_WO * sizeof(bf16_t);
    const size_t SZ_BHTD = (size_t)NBH * T_SEQ * HD * sizeof(bf16_t);
    bf16_t* qq = (bf16_t*)w;                   w += SZ_BHTD;
    bf16_t* kk = (bf16_t*)w;                   w += SZ_BHTD;
    bf16_t* vv = (bf16_t*)w;                   w += SZ_BHTD;
    bf16_t* Y  = (bf16_t*)w;                   w += SZ_BHTD;
    bf16_t* SscT = (bf16_t*)w;                 w += (size_t)NBLK * HD * HD * sizeof(bf16_t);
    bf16_t* SssT = (bf16_t*)w;                 w += (size_t)NBLK * HD * HD * sizeof(bf16_t);
    float* zc = (float*)w;                     w += (size_t)NBLK * HD * sizeof(float);
    float* zs = (float*)w;

    cvt3_kernel<<<2048, 256, 0, stream>>>(x, w_qkv, w_out, xb, wqb, wob);
    qkv_sum_kernel<<<dim3(32, 8), 1024, 0, stream>>>(
        xb, wqb, b_qkv, qq, kk, vv, SscT, SssT, zc, zs);
    chunk_out_kernel<<<NBLK, 256, 0, stream>>>(qq, kk, vv, SscT, SssT, zc, zs, Y);
    out_gemm_kernel<<<dim3(2048 / 32, 512 / 64), 256, 0, stream>>>(
        Y, wob, b_out, out);
}

// Round 5
// 128.476 us; speedup vs baseline: 1.7013x; 1.0100x over previous
//
#include <hip/hip_runtime.h>

typedef __bf16 bf16_t;
typedef __bf16 bf16x4 __attribute__((ext_vector_type(4)));
typedef __bf16 bf16x8 __attribute__((ext_vector_type(8)));
typedef float f32x4 __attribute__((ext_vector_type(4)));

#define T_SEQ 1024
#define EMB   512
#define NH    8
#define HD    64
#define BATCH 2
#define NBH   (BATCH*NH)      // 16
#define CHUNK 64
#define NCHUNK (T_SEQ/CHUNK)  // 16
#define NBLK  (NBH*NCHUNK)    // 256
#define LDA   72              // padded LDS row stride (chunk_out)
#define LDK   68              // padded LDS row stride (qkv_sum handoff)

// Identity: with ang_t = (pi/2)*t/T,
//   q_cos[t].k_cos[s] + q_sin[t].k_sin[s] = (q'[t].k'[s]) * cos(ang_t - ang_s)
//
// R17: ISOLATION ROUND. R4 (+11us vs 118.8 baseline) bundled two changes;
// this round keeps ONLY the 1024-thread qkv_sum (12 GEMM waves of 16x64,
// 3 waves/SIMD latency hiding) and reverts cvt3 + out_gemm + chunk_out to
// the exact proven baseline versions (out_gemm: 256 blocks, 64x64 tile,
// acc[2][2]/wave). One variable vs the 118.8 anchor.

// ---------------------------------------------------------------------------
// K0: fused fp32 -> bf16 convert for x, w_qkv, w_out (one dispatch).
// ---------------------------------------------------------------------------
__global__ __launch_bounds__(256) void cvt3_kernel(
    const float* __restrict__ x, const float* __restrict__ wq,
    const float* __restrict__ wo,
    bf16_t* __restrict__ xb, bf16_t* __restrict__ wqb, bf16_t* __restrict__ wob)
{
    int i = blockIdx.x * 256 + threadIdx.x;
    const float* s; bf16_t* d; int off;
    if (i < 262144)      { s = x;  d = xb;  off = i; }
    else if (i < 458752) { s = wq; d = wqb; off = i - 262144; }
    else                 { s = wo; d = wob; off = i - 458752; }
    float4 v = ((const float4*)s)[off];
    bf16x4 o;
    o[0] = (bf16_t)v.x; o[1] = (bf16_t)v.y;
    o[2] = (bf16_t)v.z; o[3] = (bf16_t)v.w;
    ((bf16x4*)d)[off] = o;
}

// ---------------------------------------------------------------------------
// K1 (qkv GEMM + chunk_sum): grid (32 m-tiles, 8 heads) = 256 blocks of
// 1024 threads. Waves 0..11: 16x64 GEMM tiles (mh = ww&3 m-quarter,
// sel = ww>>2 in {q,k,v}). k/v epilogues land tiles in LDS (stride LDK);
// after one barrier all 16 waves run chunk_sum (4 v-cols per wave).
// ---------------------------------------------------------------------------
__global__ __launch_bounds__(1024) void qkv_sum_kernel(
    const bf16_t* __restrict__ X, const bf16_t* __restrict__ W,
    const float* __restrict__ bias,
    bf16_t* __restrict__ qq, bf16_t* __restrict__ kk, bf16_t* __restrict__ vv,
    bf16_t* __restrict__ Ssc, bf16_t* __restrict__ Sss,
    float* __restrict__ zc, float* __restrict__ zs)
{
    __shared__ __align__(16) bf16_t sk[CHUNK * LDK];
    __shared__ __align__(16) bf16_t sv[CHUNK * LDK];
    __shared__ float cwt[CHUNK], swt[CHUNK];

    const int m0 = blockIdx.x * 64;
    const int h  = blockIdx.y;
    const int b  = m0 >> 10;
    const int ch = (m0 & 1023) >> 6;
    const int blk = (b * NH + h) * NCHUNK + ch;

    if (threadIdx.x < CHUNK) {
        int tg = ch * CHUNK + threadIdx.x;
        float ang = 1.5707963267948966f * (float)tg * (1.0f / (float)T_SEQ);
        cwt[threadIdx.x] = cosf(ang);
        swt[threadIdx.x] = sinf(ang);
    }

    const int ww = threadIdx.x >> 6;
    const int lane = threadIdx.x & 63;
    if (ww < 12) {
        const int mh  = ww & 3;             // m-quarter: rows mh*16..mh*16+15
        const int sel = ww >> 2;            // 0=q 1=k 2=v
        const int rsel = lane & 15;
        const int koff = (lane >> 4) * 8;
        const int n0 = sel * 512 + h * 64;
        f32x4 acc[4] = {};
        const bf16_t* Ap = X + (m0 + mh * 16 + rsel) * EMB + koff;
        const bf16_t* Bp = W + (n0 + rsel) * EMB + koff;
#pragma unroll 4
        for (int k0 = 0; k0 < EMB; k0 += 32) {
            bf16x8 af = *(const bf16x8*)(Ap + k0);
            bf16x8 bfr[4];
            for (int j = 0; j < 4; ++j)
                bfr[j] = *(const bf16x8*)(Bp + j * 16 * EMB + k0);
            for (int j = 0; j < 4; ++j)
                acc[j] = __builtin_amdgcn_mfma_f32_16x16x32_bf16(
                    af, bfr[j], acc[j], 0, 0, 0);
        }
        for (int j = 0; j < 4; ++j) {
            const int feat = j * 16 + rsel;           // 0..63 within head
            const float bn = bias[n0 + feat];
            const int tl0 = mh * 16 + (lane >> 4) * 4;  // local t, 4-aligned
            for (int r = 0; r < 4; ++r) {
                const int tl = tl0 + r;
                const int t = (m0 & 1023) + tl;
                float val = acc[j][r] + bn;
                int di = ((b * NH + h) * T_SEQ + t) * HD + feat;
                if (sel == 0) {
                    qq[di] = (bf16_t)fmaxf(val, 0.f);
                } else if (sel == 1) {
                    bf16_t kb = (bf16_t)fmaxf(val, 0.f);
                    kk[di] = kb;
                    sk[tl * LDK + feat] = kb;
                } else {
                    bf16_t vb = (bf16_t)val;
                    vv[di] = vb;
                    sv[tl * LDK + feat] = vb;
                }
            }
        }
    }
    __syncthreads();

    // ---- chunk_sum body from LDS handoff: 16 waves x 4 v-cols each ----
    const int i  = lane;
    const int jg = ww * 4;
    float ac[4], as[4];
    for (int jj = 0; jj < 4; ++jj) { ac[jj] = 0.f; as[jj] = 0.f; }
    float zca = 0.f, zsa = 0.f;
    const bool zown = (jg == 0);
    for (int t = 0; t < CHUNK; ++t) {
        float kv = (float)sk[t * LDK + i];
        float kc_ = kv * cwt[t];
        float ks_ = kv * swt[t];
        if (zown) { zca += kc_; zsa += ks_; }
        for (int jj = 0; jj < 4; ++jj) {
            float vj = (float)sv[t * LDK + jg + jj];
            ac[jj] += kc_ * vj;
            as[jj] += ks_ * vj;
        }
    }
    bf16_t* oc = Ssc + blk * HD * HD;
    bf16_t* os = Sss + blk * HD * HD;
    for (int jj = 0; jj < 4; ++jj) {
        oc[(jg + jj) * HD + i] = (bf16_t)ac[jj];   // transposed: [e][i]
        os[(jg + jj) * HD + i] = (bf16_t)as[jj];
    }
    if (zown) {
        zc[blk * HD + i] = zca;
        zs[blk * HD + i] = zsa;
    }
}

// ---------------------------------------------------------------------------
// K2: per-chunk output with on-the-fly S/z prefix (unroll-2 prefix loop)
// and the R12 bank-swizzled svT (granule rotation rot(e)=e>>3).
// ---------------------------------------------------------------------------
__global__ __launch_bounds__(256) void chunk_out_kernel(
    const bf16_t* __restrict__ qq, const bf16_t* __restrict__ kk,
    const bf16_t* __restrict__ vv,
    const bf16_t* __restrict__ SscT, const bf16_t* __restrict__ SssT,
    const float* __restrict__ zc, const float* __restrict__ zs,
    bf16_t* __restrict__ Y)
{
    const int blk = blockIdx.x;
    const int bh = blk >> 4, ch = blk & 15;
    __shared__ __align__(16) bf16_t sq [CHUNK * LDA];
    __shared__ __align__(16) bf16_t sk [CHUNK * LDA];
    __shared__ __align__(16) bf16_t svT[CHUNK * LDA];
    __shared__ __align__(16) bf16_t sct[CHUNK * LDA];
    __shared__ __align__(16) bf16_t sst[CHUNK * LDA];
    __shared__ __align__(16) bf16_t sp [CHUNK * LDA];
    __shared__ float cwt[CHUNK], swt[CHUNK], cosd[CHUNK];
    __shared__ float zcl[CHUNK], zsl[CHUNK], nrm[CHUNK];

    const int base = blk * CHUNK * HD;
    for (int i = threadIdx.x; i < CHUNK * HD / 8; i += 256) {
        int row = i >> 3, g = i & 7;
        ((uint4*)(sq + row * LDA))[g]  = ((const uint4*)(qq + base))[i];
        ((uint4*)(sk + row * LDA))[g]  = ((const uint4*)(kk + base))[i];
        // V transpose with granule rotation (conflict-free; see R12)
        bf16x8 v8 = *(const bf16x8*)(vv + base + i * 8);
        int t = i >> 3, bb = i & 7;
        int tg8 = t >> 3, tf = t & 7;
        for (int j = 0; j < 8; ++j) {
            int e = bb * 8 + j;
            int pg = (tg8 + bb) & 7;
            svT[e * LDA + pg * 8 + tf] = v8[j];
        }
    }
    // on-the-fly exclusive prefix of S over chunks < ch (fp32 acc -> bf16 LDS)
    {
        const int e0 = threadIdx.x * 16;            // flat elems [e0, e0+16)
        float accC[16], accS[16];
        for (int j = 0; j < 16; ++j) { accC[j] = 0.f; accS[j] = 0.f; }
        const int sb = bh * NCHUNK * HD * HD + e0;
#pragma unroll 2
        for (int c = 0; c < ch; ++c) {
            const bf16x8* pc = (const bf16x8*)(SscT + sb + c * HD * HD);
            const bf16x8* ps = (const bf16x8*)(SssT + sb + c * HD * HD);
            bf16x8 c0 = pc[0], c1 = pc[1], s0 = ps[0], s1 = ps[1];
            for (int j = 0; j < 8; ++j) {
                accC[j] += (float)c0[j];  accC[8 + j] += (float)c1[j];
                accS[j] += (float)s0[j];  accS[8 + j] += (float)s1[j];
            }
        }
        const int row = threadIdx.x >> 2, col = (threadIdx.x & 3) * 16;
        bf16x8 oc0, oc1, os0, os1;
        for (int j = 0; j < 8; ++j) {
            oc0[j] = (bf16_t)accC[j];  oc1[j] = (bf16_t)accC[8 + j];
            os0[j] = (bf16_t)accS[j];  os1[j] = (bf16_t)accS[8 + j];
        }
        *(bf16x8*)(sct + row * LDA + col) = oc0;
        *(bf16x8*)(sct + row * LDA + col + 8) = oc1;
        *(bf16x8*)(sst + row * LDA + col) = os0;
        *(bf16x8*)(sst + row * LDA + col + 8) = os1;
    }
    // z prefix + angle tables
    if (threadIdx.x < HD) {
        int tl = threadIdx.x;
        float s = 0.f;
        for (int c = 0; c < ch; ++c) s += zc[(bh * NCHUNK + c) * HD + tl];
        zcl[tl] = s;
        int tg = ch * CHUNK + tl;
        float angg = 1.5707963267948966f * (float)tg * (1.0f / (float)T_SEQ);
        cwt[tl] = cosf(angg);
        swt[tl] = sinf(angg);
        cosd[tl] = cosf(1.5707963267948966f * (float)tl * (1.0f / (float)T_SEQ));
    } else if (threadIdx.x < 2 * HD) {
        int i = threadIdx.x - HD;
        float s = 0.f;
        for (int c = 0; c < ch; ++c) s += zs[(bh * NCHUNK + c) * HD + i];
        zsl[i] = s;
    }
    __syncthreads();

    const int w = threadIdx.x >> 6;
    const int lane = threadIdx.x & 63;
    const int rsel = lane & 15;
    const int koff = (lane >> 4) * 8;
    const int myrow = w * 16 + rsel;

    // ---- P = q' k'^T, scale+mask, bf16 rows (wave-local) ----
    bf16x8 aq0 = *(const bf16x8*)(sq + myrow * LDA + koff);
    bf16x8 aq1 = *(const bf16x8*)(sq + myrow * LDA + koff + 32);
    for (int nt = 0; nt < 4; ++nt) {
        const int n0 = nt * 16;
        f32x4 pacc = {0.f, 0.f, 0.f, 0.f};
        bf16x8 b0 = *(const bf16x8*)(sk + (n0 + rsel) * LDA + koff);
        bf16x8 b1 = *(const bf16x8*)(sk + (n0 + rsel) * LDA + koff + 32);
        pacc = __builtin_amdgcn_mfma_f32_16x16x32_bf16(aq0, b0, pacc, 0, 0, 0);
        pacc = __builtin_amdgcn_mfma_f32_16x16x32_bf16(aq1, b1, pacc, 0, 0, 0);
        const int s = n0 + (lane & 15);
        const int tb = w * 16 + (lane >> 4) * 4;
        for (int r = 0; r < 4; ++r) {
            int t = tb + r;
            float p = (s <= t) ? pacc[r] * cosd[t - s] : 0.f;
            sp[t * LDA + s] = (bf16_t)p;
        }
    }

    // ---- nrm (lanes 0..15 of each wave; rows wave-local) ----
    if (lane < 16) {
        int row = w * 16 + lane;
        float nv = 0.f;
        const bf16x8* pr = (const bf16x8*)(sp + row * LDA);
        for (int g = 0; g < 8; ++g) {
            bf16x8 pv = pr[g];
            for (int j = 0; j < 8; ++j) nv += (float)pv[j];
        }
        float cwr = cwt[row], swr = swt[row];
        const bf16x8* qr = (const bf16x8*)(sq + row * LDA);
        for (int g = 0; g < 8; ++g) {
            bf16x8 qv = qr[g];
            for (int j = 0; j < 8; ++j)
                nv += (float)qv[j] * (cwr * zcl[g * 8 + j] + swr * zsl[g * 8 + j]);
        }
        nrm[row] = nv;
    }

    // ---- ctx = P@V + q'c@Sc + q's@Ss ----
    const float cwq = cwt[myrow], swq = swt[myrow];
    bf16x8 qc0, qc1, qs0, qs1;
    for (int j = 0; j < 8; ++j) {
        qc0[j] = (bf16_t)((float)aq0[j] * cwq);
        qc1[j] = (bf16_t)((float)aq1[j] * cwq);
        qs0[j] = (bf16_t)((float)aq0[j] * swq);
        qs1[j] = (bf16_t)((float)aq1[j] * swq);
    }
    bf16x8 ap0 = *(const bf16x8*)(sp + myrow * LDA + koff);
    bf16x8 ap1 = *(const bf16x8*)(sp + myrow * LDA + koff + 32);

    const int b = bh >> 3, h = bh & 7;
    const int g0 = koff >> 3;                       // logical granule 0..3
    for (int nt = 0; nt < 4; ++nt) {
        const int n0 = nt * 16;
        const int ee = n0 + rsel;
        const int rot = (ee >> 3) & 7;
        const bf16_t* bvp0 = svT + ee * LDA + (((g0 + rot) & 7) << 3);
        const bf16_t* bvp1 = svT + ee * LDA + (((g0 + 4 + rot) & 7) << 3);
        const bf16_t* bcp = sct + ee * LDA + koff;
        const bf16_t* bsp = sst + ee * LDA + koff;
        f32x4 acc = {0.f, 0.f, 0.f, 0.f};
        acc = __builtin_amdgcn_mfma_f32_16x16x32_bf16(ap0, *(const bf16x8*)(bvp0), acc, 0, 0, 0);
        acc = __builtin_amdgcn_mfma_f32_16x16x32_bf16(ap1, *(const bf16x8*)(bvp1), acc, 0, 0, 0);
        acc = __builtin_amdgcn_mfma_f32_16x16x32_bf16(qc0, *(const bf16x8*)(bcp), acc, 0, 0, 0);
        acc = __builtin_amdgcn_mfma_f32_16x16x32_bf16(qc1, *(const bf16x8*)(bcp + 32), acc, 0, 0, 0);
        acc = __builtin_amdgcn_mfma_f32_16x16x32_bf16(qs0, *(const bf16x8*)(bsp), acc, 0, 0, 0);
        acc = __builtin_amdgcn_mfma_f32_16x16x32_bf16(qs1, *(const bf16x8*)(bsp + 32), acc, 0, 0, 0);
        const int col = n0 + (lane & 15);
        const int tb = w * 16 + (lane >> 4) * 4;
        for (int r = 0; r < 4; ++r) {
            int row = tb + r;
            float inv = 1.0f / (nrm[row] + 1e-6f);
            int tg = ch * CHUNK + row;
            Y[((b * T_SEQ + tg) * EMB) + h * HD + col] = (bf16_t)(acc[r] * inv);
        }
    }
}

// ---------------------------------------------------------------------------
// K3: out = Y @ w_out^T + b_out, register-blocked 2x2 per wave, fp32 out.
// (exact baseline version: 256 blocks of 64x64)
// ---------------------------------------------------------------------------
__global__ __launch_bounds__(256) void out_gemm_kernel(
    const bf16_t* __restrict__ Yb, const bf16_t* __restrict__ W,
    const float* __restrict__ bias, float* __restrict__ out)
{
    const int w = threadIdx.x >> 6;
    const int lane = threadIdx.x & 63;
    const int rsel = lane & 15;
    const int koff = (lane >> 4) * 8;
    const int m0 = blockIdx.x * 64 + (w & 1) * 32;
    const int n0 = blockIdx.y * 64 + (w >> 1) * 32;
    f32x4 acc[2][2] = {};
    const bf16_t* Ap = Yb + (m0 + rsel) * EMB + koff;
    const bf16_t* Bp = W + (n0 + rsel) * EMB + koff;
#pragma unroll 8
    for (int k0 = 0; k0 < EMB; k0 += 32) {
        bf16x8 af[2], bfr[2];
        for (int i = 0; i < 2; ++i)
            af[i] = *(const bf16x8*)(Ap + i * 16 * EMB + k0);
        for (int j = 0; j < 2; ++j)
            bfr[j] = *(const bf16x8*)(Bp + j * 16 * EMB + k0);
        for (int i = 0; i < 2; ++i)
            for (int j = 0; j < 2; ++j)
                acc[i][j] = __builtin_amdgcn_mfma_f32_16x16x32_bf16(
                    af[i], bfr[j], acc[i][j], 0, 0, 0);
    }
    for (int j = 0; j < 2; ++j) {
        const int n = n0 + j * 16 + rsel;
        const float bn = bias[n];
        for (int i = 0; i < 2; ++i) {
            const int mb = m0 + i * 16 + (lane >> 4) * 4;
            for (int r = 0; r < 4; ++r)
                out[(mb + r) * EMB + n] = acc[i][j][r] + bn;
        }
    }
}

extern "C" void kernel_launch(void* const* d_in, const int* in_sizes, int n_in,
                              void* d_out, int out_size, void* d_ws, size_t ws_size,
                              hipStream_t stream) {
    const float* x     = (const float*)d_in[0];
    const float* w_qkv = (const float*)d_in[1];
    const float* b_qkv = (const float*)d_in[2];
    const float* w_out = (const float*)d_in[3];
    const float* b_out = (const float*)d_in[4];
    float* out = (float*)d_out;

    char* w = (char*)d_ws;
    const size_t N_X   = (size_t)BATCH * T_SEQ * EMB;
    const size_t N_WQ  = (size_t)3 * EMB * EMB;
    const size_t N_WO  = (size_t)EMB * EMB;
    bf16_t* xb   = (bf16_t*)w;                 w += N_X  * sizeof(bf16_t);
    bf16_t* wqb  = (bf16_t*)w;                 w += N_WQ * sizeof(bf16_t);
    bf16_t* wob  = (bf16_t*)w;                 w += N_WO * sizeof(bf16_t);
    const size_t SZ_BHTD = (size_t)NBH * T_SEQ * HD * sizeof(bf16_t);
    bf16_t* qq = (bf16_t*)w;                   w += SZ_BHTD;
    bf16_t* kk = (bf16_t*)w;                   w += SZ_BHTD;
    bf16_t* vv = (bf16_t*)w;                   w += SZ_BHTD;
    bf16_t* Y  = (bf16_t*)w;                   w += SZ_BHTD;
    bf16_t* SscT = (bf16_t*)w;                 w += (size_t)NBLK * HD * HD * sizeof(bf16_t);
    bf16_t* SssT = (bf16_t*)w;                 w += (size_t)NBLK * HD * HD * sizeof(bf16_t);
    float* zc = (float*)w;                     w += (size_t)NBLK * HD * sizeof(float);
    float* zs = (float*)w;

    cvt3_kernel<<<2048, 256, 0, stream>>>(x, w_qkv, w_out, xb, wqb, wob);
    qkv_sum_kernel<<<dim3(32, 8), 1024, 0, stream>>>(
        xb, wqb, b_qkv, qq, kk, vv, SscT, SssT, zc, zs);
    chunk_out_kernel<<<NBLK, 256, 0, stream>>>(qq, kk, vv, SscT, SssT, zc, zs, Y);
    out_gemm_kernel<<<dim3(2048 / 64, 512 / 64), 256, 0, stream>>>(
        Y, wob, b_out, out);
}

// Round 6
// 113.835 us; speedup vs baseline: 1.9201x; 1.1286x over previous
//
#include <hip/hip_runtime.h>

typedef __bf16 bf16_t;
typedef __bf16 bf16x4 __attribute__((ext_vector_type(4)));
typedef __bf16 bf16x8 __attribute__((ext_vector_type(8)));
typedef float f32x4 __attribute__((ext_vector_type(4)));

#define T_SEQ 1024
#define EMB   512
#define NH    8
#define HD    64
#define BATCH 2
#define NBH   (BATCH*NH)      // 16
#define CHUNK 64
#define NCHUNK (T_SEQ/CHUNK)  // 16
#define NBLK  (NBH*NCHUNK)    // 256
#define LDA   72              // padded LDS row stride (chunk_out)
#define LDK   68              // padded LDS row stride (qkv_sum handoff + P bufs)

// Identity: with ang_t = (pi/2)*t/T,
//   q_cos[t].k_cos[s] + q_sin[t].k_sin[s] = (q'[t].k'[s]) * cos(ang_t - ang_s)
//
// R18: qkv_sum K-SPLIT. R5 proved m-splitting regresses (2.5x loads); R2
// proved cost tracks load count. K-splitting duplicates ZERO loads: 512
// threads, q/k/v each owned by TWO waves (K-halves, acc[4][4], 8 k-steps),
// 6 GEMM waves = 2/SIMD on 3 SIMDs (was 1/SIMD on 3), same 384 loads/block.
// Partials reduced via two padded f32 LDS buffers ([feat][t] layout,
// f32x4 rows, 2-way-bank-free). v,k reduced first (chunk_sum needs sk/sv);
// q partial staged after Pa frees. cvt3/chunk_out/out_gemm = exact baseline.

// ---------------------------------------------------------------------------
// K0: fused fp32 -> bf16 convert for x, w_qkv, w_out (one dispatch).
// ---------------------------------------------------------------------------
__global__ __launch_bounds__(256) void cvt3_kernel(
    const float* __restrict__ x, const float* __restrict__ wq,
    const float* __restrict__ wo,
    bf16_t* __restrict__ xb, bf16_t* __restrict__ wqb, bf16_t* __restrict__ wob)
{
    int i = blockIdx.x * 256 + threadIdx.x;
    const float* s; bf16_t* d; int off;
    if (i < 262144)      { s = x;  d = xb;  off = i; }
    else if (i < 458752) { s = wq; d = wqb; off = i - 262144; }
    else                 { s = wo; d = wob; off = i - 458752; }
    float4 v = ((const float4*)s)[off];
    bf16x4 o;
    o[0] = (bf16_t)v.x; o[1] = (bf16_t)v.y;
    o[2] = (bf16_t)v.z; o[3] = (bf16_t)v.w;
    ((bf16x4*)d)[off] = o;
}

// ---------------------------------------------------------------------------
// K1 (qkv GEMM + chunk_sum): grid (32 m-tiles, 8 heads) = 256 blocks of
// 512 threads. Wave ww: sel = ww&3 (0=q 1=k 2=v 3=idle), kh = ww>>2.
// Each GEMM wave: 64x64 output tile over its K-half (k in [kh*256, +256)).
// Reduction: w6(v)->Pa, w5(k)->Pb | B1 | w2: v+Pa -> vv,sv ; w1: k+Pb ->
// kk,sk | B2 | w4(q)->Pa | B3 | w0: q+Pa -> qq ; all: chunk_sum from LDS.
// ---------------------------------------------------------------------------
__global__ __launch_bounds__(512) void qkv_sum_kernel(
    const bf16_t* __restrict__ X, const bf16_t* __restrict__ W,
    const float* __restrict__ bias,
    bf16_t* __restrict__ qq, bf16_t* __restrict__ kk, bf16_t* __restrict__ vv,
    bf16_t* __restrict__ Ssc, bf16_t* __restrict__ Sss,
    float* __restrict__ zc, float* __restrict__ zs)
{
    __shared__ __align__(16) bf16_t sk[CHUNK * LDK];
    __shared__ __align__(16) bf16_t sv[CHUNK * LDK];
    __shared__ __align__(16) float  Pa[CHUNK * LDK];   // [feat][t], stride 68
    __shared__ __align__(16) float  Pb[CHUNK * LDK];
    __shared__ float cwt[CHUNK], swt[CHUNK];

    const int m0 = blockIdx.x * 64;
    const int h  = blockIdx.y;
    const int b  = m0 >> 10;
    const int ch = (m0 & 1023) >> 6;
    const int blk = (b * NH + h) * NCHUNK + ch;

    if (threadIdx.x < CHUNK) {
        int tg = ch * CHUNK + threadIdx.x;
        float ang = 1.5707963267948966f * (float)tg * (1.0f / (float)T_SEQ);
        cwt[threadIdx.x] = cosf(ang);
        swt[threadIdx.x] = sinf(ang);
    }

    const int ww   = threadIdx.x >> 6;
    const int lane = threadIdx.x & 63;
    const int sel  = ww & 3;            // 0=q 1=k 2=v 3=idle
    const int kh   = ww >> 2;           // K-half
    const int rsel = lane & 15;
    const int koff = (lane >> 4) * 8;
    const int tl0g = (lane >> 4) * 4;   // 4-aligned t sub-offset

    f32x4 acc[4][4] = {};
    if (sel < 3) {
        const int n0 = sel * 512 + h * 64;
        const int kb = kh * 256;
        const bf16_t* Ap = X + (m0 + rsel) * EMB + kb + koff;
        const bf16_t* Bp = W + (n0 + rsel) * EMB + kb + koff;
#pragma unroll 4
        for (int k0 = 0; k0 < 256; k0 += 32) {
            bf16x8 af[4], bfr[4];
            for (int i = 0; i < 4; ++i)
                af[i] = *(const bf16x8*)(Ap + i * 16 * EMB + k0);
            for (int j = 0; j < 4; ++j)
                bfr[j] = *(const bf16x8*)(Bp + j * 16 * EMB + k0);
            for (int i = 0; i < 4; ++i)
                for (int j = 0; j < 4; ++j)
                    acc[i][j] = __builtin_amdgcn_mfma_f32_16x16x32_bf16(
                        af[i], bfr[j], acc[i][j], 0, 0, 0);
        }
    }

    // interval 1: second-half v,k waves publish partials (P[feat][t], f32x4)
    if (kh == 1 && (sel == 1 || sel == 2)) {
        float* P = (sel == 2) ? Pa : Pb;
        for (int j = 0; j < 4; ++j)
            for (int i = 0; i < 4; ++i)
                *(f32x4*)(P + (j * 16 + rsel) * LDK + i * 16 + tl0g) = acc[i][j];
    }
    __syncthreads();                                   // B1

    // interval 2: k,v owners reduce + epilogue (sk/sv needed by chunk_sum)
    if (kh == 0 && (sel == 1 || sel == 2)) {
        const float* P = (sel == 2) ? Pa : Pb;
        const int n0 = sel * 512 + h * 64;
        for (int j = 0; j < 4; ++j) {
            const int feat = j * 16 + rsel;
            const float bn = bias[n0 + feat];
            for (int i = 0; i < 4; ++i) {
                const int tl0 = i * 16 + tl0g;
                f32x4 p = *(const f32x4*)(P + feat * LDK + tl0);
                for (int r = 0; r < 4; ++r) {
                    const int tl = tl0 + r;
                    const int t = (m0 & 1023) + tl;
                    float val = acc[i][j][r] + p[r] + bn;
                    int di = ((b * NH + h) * T_SEQ + t) * HD + feat;
                    if (sel == 1) {
                        bf16_t kb2 = (bf16_t)fmaxf(val, 0.f);
                        kk[di] = kb2;
                        sk[tl * LDK + feat] = kb2;
                    } else {
                        bf16_t vb = (bf16_t)val;
                        vv[di] = vb;
                        sv[tl * LDK + feat] = vb;
                    }
                }
            }
        }
    }
    __syncthreads();                                   // B2

    // interval 3: q second-half publishes into Pa (free after B2)
    if (kh == 1 && sel == 0) {
        for (int j = 0; j < 4; ++j)
            for (int i = 0; i < 4; ++i)
                *(f32x4*)(Pa + (j * 16 + rsel) * LDK + i * 16 + tl0g) = acc[i][j];
    }
    __syncthreads();                                   // B3

    // q owner reduces + stores (global only; other waves proceed to chunk_sum)
    if (kh == 0 && sel == 0) {
        const int n0 = h * 64;
        for (int j = 0; j < 4; ++j) {
            const int feat = j * 16 + rsel;
            const float bn = bias[n0 + feat];
            for (int i = 0; i < 4; ++i) {
                const int tl0 = i * 16 + tl0g;
                f32x4 p = *(const f32x4*)(Pa + feat * LDK + tl0);
                for (int r = 0; r < 4; ++r) {
                    const int tl = tl0 + r;
                    const int t = (m0 & 1023) + tl;
                    float val = acc[i][j][r] + p[r] + bn;
                    int di = ((b * NH + h) * T_SEQ + t) * HD + feat;
                    qq[di] = (bf16_t)fmaxf(val, 0.f);
                }
            }
        }
    }

    // ---- chunk_sum body from LDS handoff: 8 waves x 8 v-cols each ----
    const int i  = lane;
    const int jg = ww * 8;
    float ac[8], as[8];
    for (int jj = 0; jj < 8; ++jj) { ac[jj] = 0.f; as[jj] = 0.f; }
    float zca = 0.f, zsa = 0.f;
    const bool zown = (jg == 0);
    for (int t = 0; t < CHUNK; ++t) {
        float kv = (float)sk[t * LDK + i];
        float kc_ = kv * cwt[t];
        float ks_ = kv * swt[t];
        if (zown) { zca += kc_; zsa += ks_; }
        for (int jj = 0; jj < 8; ++jj) {
            float vj = (float)sv[t * LDK + jg + jj];
            ac[jj] += kc_ * vj;
            as[jj] += ks_ * vj;
        }
    }
    bf16_t* oc = Ssc + blk * HD * HD;
    bf16_t* os = Sss + blk * HD * HD;
    for (int jj = 0; jj < 8; ++jj) {
        oc[(jg + jj) * HD + i] = (bf16_t)ac[jj];   // transposed: [e][i]
        os[(jg + jj) * HD + i] = (bf16_t)as[jj];
    }
    if (zown) {
        zc[blk * HD + i] = zca;
        zs[blk * HD + i] = zsa;
    }
}

// ---------------------------------------------------------------------------
// K2: per-chunk output with on-the-fly S/z prefix (unroll-2 prefix loop)
// and the R12 bank-swizzled svT (granule rotation rot(e)=e>>3).
// ---------------------------------------------------------------------------
__global__ __launch_bounds__(256) void chunk_out_kernel(
    const bf16_t* __restrict__ qq, const bf16_t* __restrict__ kk,
    const bf16_t* __restrict__ vv,
    const bf16_t* __restrict__ SscT, const bf16_t* __restrict__ SssT,
    const float* __restrict__ zc, const float* __restrict__ zs,
    bf16_t* __restrict__ Y)
{
    const int blk = blockIdx.x;
    const int bh = blk >> 4, ch = blk & 15;
    __shared__ __align__(16) bf16_t sq [CHUNK * LDA];
    __shared__ __align__(16) bf16_t sk [CHUNK * LDA];
    __shared__ __align__(16) bf16_t svT[CHUNK * LDA];
    __shared__ __align__(16) bf16_t sct[CHUNK * LDA];
    __shared__ __align__(16) bf16_t sst[CHUNK * LDA];
    __shared__ __align__(16) bf16_t sp [CHUNK * LDA];
    __shared__ float cwt[CHUNK], swt[CHUNK], cosd[CHUNK];
    __shared__ float zcl[CHUNK], zsl[CHUNK], nrm[CHUNK];

    const int base = blk * CHUNK * HD;
    for (int i = threadIdx.x; i < CHUNK * HD / 8; i += 256) {
        int row = i >> 3, g = i & 7;
        ((uint4*)(sq + row * LDA))[g]  = ((const uint4*)(qq + base))[i];
        ((uint4*)(sk + row * LDA))[g]  = ((const uint4*)(kk + base))[i];
        // V transpose with granule rotation (conflict-free; see R12)
        bf16x8 v8 = *(const bf16x8*)(vv + base + i * 8);
        int t = i >> 3, bb = i & 7;
        int tg8 = t >> 3, tf = t & 7;
        for (int j = 0; j < 8; ++j) {
            int e = bb * 8 + j;
            int pg = (tg8 + bb) & 7;
            svT[e * LDA + pg * 8 + tf] = v8[j];
        }
    }
    // on-the-fly exclusive prefix of S over chunks < ch (fp32 acc -> bf16 LDS)
    {
        const int e0 = threadIdx.x * 16;            // flat elems [e0, e0+16)
        float accC[16], accS[16];
        for (int j = 0; j < 16; ++j) { accC[j] = 0.f; accS[j] = 0.f; }
        const int sb = bh * NCHUNK * HD * HD + e0;
#pragma unroll 2
        for (int c = 0; c < ch; ++c) {
            const bf16x8* pc = (const bf16x8*)(SscT + sb + c * HD * HD);
            const bf16x8* ps = (const bf16x8*)(SssT + sb + c * HD * HD);
            bf16x8 c0 = pc[0], c1 = pc[1], s0 = ps[0], s1 = ps[1];
            for (int j = 0; j < 8; ++j) {
                accC[j] += (float)c0[j];  accC[8 + j] += (float)c1[j];
                accS[j] += (float)s0[j];  accS[8 + j] += (float)s1[j];
            }
        }
        const int row = threadIdx.x >> 2, col = (threadIdx.x & 3) * 16;
        bf16x8 oc0, oc1, os0, os1;
        for (int j = 0; j < 8; ++j) {
            oc0[j] = (bf16_t)accC[j];  oc1[j] = (bf16_t)accC[8 + j];
            os0[j] = (bf16_t)accS[j];  os1[j] = (bf16_t)accS[8 + j];
        }
        *(bf16x8*)(sct + row * LDA + col) = oc0;
        *(bf16x8*)(sct + row * LDA + col + 8) = oc1;
        *(bf16x8*)(sst + row * LDA + col) = os0;
        *(bf16x8*)(sst + row * LDA + col + 8) = os1;
    }
    // z prefix + angle tables
    if (threadIdx.x < HD) {
        int tl = threadIdx.x;
        float s = 0.f;
        for (int c = 0; c < ch; ++c) s += zc[(bh * NCHUNK + c) * HD + tl];
        zcl[tl] = s;
        int tg = ch * CHUNK + tl;
        float angg = 1.5707963267948966f * (float)tg * (1.0f / (float)T_SEQ);
        cwt[tl] = cosf(angg);
        swt[tl] = sinf(angg);
        cosd[tl] = cosf(1.5707963267948966f * (float)tl * (1.0f / (float)T_SEQ));
    } else if (threadIdx.x < 2 * HD) {
        int i = threadIdx.x - HD;
        float s = 0.f;
        for (int c = 0; c < ch; ++c) s += zs[(bh * NCHUNK + c) * HD + i];
        zsl[i] = s;
    }
    __syncthreads();

    const int w = threadIdx.x >> 6;
    const int lane = threadIdx.x & 63;
    const int rsel = lane & 15;
    const int koff = (lane >> 4) * 8;
    const int myrow = w * 16 + rsel;

    // ---- P = q' k'^T, scale+mask, bf16 rows (wave-local) ----
    bf16x8 aq0 = *(const bf16x8*)(sq + myrow * LDA + koff);
    bf16x8 aq1 = *(const bf16x8*)(sq + myrow * LDA + koff + 32);
    for (int nt = 0; nt < 4; ++nt) {
        const int n0 = nt * 16;
        f32x4 pacc = {0.f, 0.f, 0.f, 0.f};
        bf16x8 b0 = *(const bf16x8*)(sk + (n0 + rsel) * LDA + koff);
        bf16x8 b1 = *(const bf16x8*)(sk + (n0 + rsel) * LDA + koff + 32);
        pacc = __builtin_amdgcn_mfma_f32_16x16x32_bf16(aq0, b0, pacc, 0, 0, 0);
        pacc = __builtin_amdgcn_mfma_f32_16x16x32_bf16(aq1, b1, pacc, 0, 0, 0);
        const int s = n0 + (lane & 15);
        const int tb = w * 16 + (lane >> 4) * 4;
        for (int r = 0; r < 4; ++r) {
            int t = tb + r;
            float p = (s <= t) ? pacc[r] * cosd[t - s] : 0.f;
            sp[t * LDA + s] = (bf16_t)p;
        }
    }

    // ---- nrm (lanes 0..15 of each wave; rows wave-local) ----
    if (lane < 16) {
        int row = w * 16 + lane;
        float nv = 0.f;
        const bf16x8* pr = (const bf16x8*)(sp + row * LDA);
        for (int g = 0; g < 8; ++g) {
            bf16x8 pv = pr[g];
            for (int j = 0; j < 8; ++j) nv += (float)pv[j];
        }
        float cwr = cwt[row], swr = swt[row];
        const bf16x8* qr = (const bf16x8*)(sq + row * LDA);
        for (int g = 0; g < 8; ++g) {
            bf16x8 qv = qr[g];
            for (int j = 0; j < 8; ++j)
                nv += (float)qv[j] * (cwr * zcl[g * 8 + j] + swr * zsl[g * 8 + j]);
        }
        nrm[row] = nv;
    }

    // ---- ctx = P@V + q'c@Sc + q's@Ss ----
    const float cwq = cwt[myrow], swq = swt[myrow];
    bf16x8 qc0, qc1, qs0, qs1;
    for (int j = 0; j < 8; ++j) {
        qc0[j] = (bf16_t)((float)aq0[j] * cwq);
        qc1[j] = (bf16_t)((float)aq1[j] * cwq);
        qs0[j] = (bf16_t)((float)aq0[j] * swq);
        qs1[j] = (bf16_t)((float)aq1[j] * swq);
    }
    bf16x8 ap0 = *(const bf16x8*)(sp + myrow * LDA + koff);
    bf16x8 ap1 = *(const bf16x8*)(sp + myrow * LDA + koff + 32);

    const int b = bh >> 3, h = bh & 7;
    const int g0 = koff >> 3;                       // logical granule 0..3
    for (int nt = 0; nt < 4; ++nt) {
        const int n0 = nt * 16;
        const int ee = n0 + rsel;
        const int rot = (ee >> 3) & 7;
        const bf16_t* bvp0 = svT + ee * LDA + (((g0 + rot) & 7) << 3);
        const bf16_t* bvp1 = svT + ee * LDA + (((g0 + 4 + rot) & 7) << 3);
        const bf16_t* bcp = sct + ee * LDA + koff;
        const bf16_t* bsp = sst + ee * LDA + koff;
        f32x4 acc = {0.f, 0.f, 0.f, 0.f};
        acc = __builtin_amdgcn_mfma_f32_16x16x32_bf16(ap0, *(const bf16x8*)(bvp0), acc, 0, 0, 0);
        acc = __builtin_amdgcn_mfma_f32_16x16x32_bf16(ap1, *(const bf16x8*)(bvp1), acc, 0, 0, 0);
        acc = __builtin_amdgcn_mfma_f32_16x16x32_bf16(qc0, *(const bf16x8*)(bcp), acc, 0, 0, 0);
        acc = __builtin_amdgcn_mfma_f32_16x16x32_bf16(qc1, *(const bf16x8*)(bcp + 32), acc, 0, 0, 0);
        acc = __builtin_amdgcn_mfma_f32_16x16x32_bf16(qs0, *(const bf16x8*)(bsp), acc, 0, 0, 0);
        acc = __builtin_amdgcn_mfma_f32_16x16x32_bf16(qs1, *(const bf16x8*)(bsp + 32), acc, 0, 0, 0);
        const int col = n0 + (lane & 15);
        const int tb = w * 16 + (lane >> 4) * 4;
        for (int r = 0; r < 4; ++r) {
            int row = tb + r;
            float inv = 1.0f / (nrm[row] + 1e-6f);
            int tg = ch * CHUNK + row;
            Y[((b * T_SEQ + tg) * EMB) + h * HD + col] = (bf16_t)(acc[r] * inv);
        }
    }
}

// ---------------------------------------------------------------------------
// K3: out = Y @ w_out^T + b_out, register-blocked 2x2 per wave, fp32 out.
// (exact baseline version: 256 blocks of 64x64)
// ---------------------------------------------------------------------------
__global__ __launch_bounds__(256) void out_gemm_kernel(
    const bf16_t* __restrict__ Yb, const bf16_t* __restrict__ W,
    const float* __restrict__ bias, float* __restrict__ out)
{
    const int w = threadIdx.x >> 6;
    const int lane = threadIdx.x & 63;
    const int rsel = lane & 15;
    const int koff = (lane >> 4) * 8;
    const int m0 = blockIdx.x * 64 + (w & 1) * 32;
    const int n0 = blockIdx.y * 64 + (w >> 1) * 32;
    f32x4 acc[2][2] = {};
    const bf16_t* Ap = Yb + (m0 + rsel) * EMB + koff;
    const bf16_t* Bp = W + (n0 + rsel) * EMB + koff;
#pragma unroll 8
    for (int k0 = 0; k0 < EMB; k0 += 32) {
        bf16x8 af[2], bfr[2];
        for (int i = 0; i < 2; ++i)
            af[i] = *(const bf16x8*)(Ap + i * 16 * EMB + k0);
        for (int j = 0; j < 2; ++j)
            bfr[j] = *(const bf16x8*)(Bp + j * 16 * EMB + k0);
        for (int i = 0; i < 2; ++i)
            for (int j = 0; j < 2; ++j)
                acc[i][j] = __builtin_amdgcn_mfma_f32_16x16x32_bf16(
                    af[i], bfr[j], acc[i][j], 0, 0, 0);
    }
    for (int j = 0; j < 2; ++j) {
        const int n = n0 + j * 16 + rsel;
        const float bn = bias[n];
        for (int i = 0; i < 2; ++i) {
            const int mb = m0 + i * 16 + (lane >> 4) * 4;
            for (int r = 0; r < 4; ++r)
                out[(mb + r) * EMB + n] = acc[i][j][r] + bn;
        }
    }
}

extern "C" void kernel_launch(void* const* d_in, const int* in_sizes, int n_in,
                              void* d_out, int out_size, void* d_ws, size_t ws_size,
                              hipStream_t stream) {
    const float* x     = (const float*)d_in[0];
    const float* w_qkv = (const float*)d_in[1];
    const float* b_qkv = (const float*)d_in[2];
    const float* w_out = (const float*)d_in[3];
    const float* b_out = (const float*)d_in[4];
    float* out = (float*)d_out;

    char* w = (char*)d_ws;
    const size_t N_X   = (size_t)BATCH * T_SEQ * EMB;
    const size_t N_WQ  = (size_t)3 * EMB * EMB;
    const size_t N_WO  = (size_t)EMB * EMB;
    bf16_t* xb   = (bf16_t*)w;                 w += N_X  * sizeof(bf16_t);
    bf16_t* wqb  = (bf16_t*)w;                 w += N_WQ * sizeof(bf16_t);
    bf16_t* wob  = (bf16_t*)w;                 w += N_WO * sizeof(bf16_t);
    const size_t SZ_BHTD = (size_t)NBH * T_SEQ * HD * sizeof(bf16_t);
    bf16_t* qq = (bf16_t*)w;                   w += SZ_BHTD;
    bf16_t* kk = (bf16_t*)w;                   w += SZ_BHTD;
    bf16_t* vv = (bf16_t*)w;                   w += SZ_BHTD;
    bf16_t* Y  = (bf16_t*)w;                   w += SZ_BHTD;
    bf16_t* SscT = (bf16_t*)w;                 w += (size_t)NBLK * HD * HD * sizeof(bf16_t);
    bf16_t* SssT = (bf16_t*)w;                 w += (size_t)NBLK * HD * HD * sizeof(bf16_t);
    float* zc = (float*)w;                     w += (size_t)NBLK * HD * sizeof(float);
    float* zs = (float*)w;

    cvt3_kernel<<<2048, 256, 0, stream>>>(x, w_qkv, w_out, xb, wqb, wob);
    qkv_sum_kernel<<<dim3(32, 8), 512, 0, stream>>>(
        xb, wqb, b_qkv, qq, kk, vv, SscT, SssT, zc, zs);
    chunk_out_kernel<<<NBLK, 256, 0, stream>>>(qq, kk, vv, SscT, SssT, zc, zs, Y);
    out_gemm_kernel<<<dim3(2048 / 64, 512 / 64), 256, 0, stream>>>(
        Y, wob, b_out, out);
}

// Round 7
// 113.170 us; speedup vs baseline: 1.9314x; 1.0059x over previous
//
#include <hip/hip_runtime.h>

typedef __bf16 bf16_t;
typedef __bf16 bf16x4 __attribute__((ext_vector_type(4)));
typedef __bf16 bf16x8 __attribute__((ext_vector_type(8)));
typedef float f32x4 __attribute__((ext_vector_type(4)));

#define T_SEQ 1024
#define EMB   512
#define NH    8
#define HD    64
#define BATCH 2
#define NBH   (BATCH*NH)      // 16
#define CHUNK 64
#define NCHUNK (T_SEQ/CHUNK)  // 16
#define NBLK  (NBH*NCHUNK)    // 256
#define LDA   72              // padded LDS row stride (chunk_out)
#define LDK   68              // padded LDS row stride (qkv_sum handoff + P bufs)

// Identity: with ang_t = (pi/2)*t/T,
//   q_cos[t].k_cos[s] + q_sin[t].k_sin[s] = (q'[t].k'[s]) * cos(ang_t - ang_s)
//
// R19: K-split out_gemm (same recipe that won R6 on qkv: wave concurrency
// at CONSTANT load count). out_gemm: 512 threads, 8 waves = quadrant (w&3)
// x K-half (w>>2); each wave 32x32 tile over K=256 (8 k-iters), 256 total
// load-instrs/block (unchanged vs baseline 4-wave). kh=1 publishes f32
// partials to LDS (stride-36 f32 cols, 16B-aligned f32x4), 1 barrier,
// kh=0 reduces + bias + store. qkv_sum keeps the R18 2-way K-split.

// ---------------------------------------------------------------------------
// K0: fused fp32 -> bf16 convert for x, w_qkv, w_out (one dispatch).
// ---------------------------------------------------------------------------
__global__ __launch_bounds__(256) void cvt3_kernel(
    const float* __restrict__ x, const float* __restrict__ wq,
    const float* __restrict__ wo,
    bf16_t* __restrict__ xb, bf16_t* __restrict__ wqb, bf16_t* __restrict__ wob)
{
    int i = blockIdx.x * 256 + threadIdx.x;
    const float* s; bf16_t* d; int off;
    if (i < 262144)      { s = x;  d = xb;  off = i; }
    else if (i < 458752) { s = wq; d = wqb; off = i - 262144; }
    else                 { s = wo; d = wob; off = i - 458752; }
    float4 v = ((const float4*)s)[off];
    bf16x4 o;
    o[0] = (bf16_t)v.x; o[1] = (bf16_t)v.y;
    o[2] = (bf16_t)v.z; o[3] = (bf16_t)v.w;
    ((bf16x4*)d)[off] = o;
}

// ---------------------------------------------------------------------------
// K1 (qkv GEMM + chunk_sum): grid (32 m-tiles, 8 heads) = 256 blocks of
// 512 threads. Wave ww: sel = ww&3 (0=q 1=k 2=v 3=idle), kh = ww>>2.
// Each GEMM wave: 64x64 output tile over its K-half (k in [kh*256, +256)).
// Reduction: w6(v)->Pa, w5(k)->Pb | B1 | w2: v+Pa -> vv,sv ; w1: k+Pb ->
// kk,sk | B2 | w4(q)->Pa | B3 | w0: q+Pa -> qq ; all: chunk_sum from LDS.
// ---------------------------------------------------------------------------
__global__ __launch_bounds__(512) void qkv_sum_kernel(
    const bf16_t* __restrict__ X, const bf16_t* __restrict__ W,
    const float* __restrict__ bias,
    bf16_t* __restrict__ qq, bf16_t* __restrict__ kk, bf16_t* __restrict__ vv,
    bf16_t* __restrict__ Ssc, bf16_t* __restrict__ Sss,
    float* __restrict__ zc, float* __restrict__ zs)
{
    __shared__ __align__(16) bf16_t sk[CHUNK * LDK];
    __shared__ __align__(16) bf16_t sv[CHUNK * LDK];
    __shared__ __align__(16) float  Pa[CHUNK * LDK];   // [feat][t], stride 68
    __shared__ __align__(16) float  Pb[CHUNK * LDK];
    __shared__ float cwt[CHUNK], swt[CHUNK];

    const int m0 = blockIdx.x * 64;
    const int h  = blockIdx.y;
    const int b  = m0 >> 10;
    const int ch = (m0 & 1023) >> 6;
    const int blk = (b * NH + h) * NCHUNK + ch;

    if (threadIdx.x < CHUNK) {
        int tg = ch * CHUNK + threadIdx.x;
        float ang = 1.5707963267948966f * (float)tg * (1.0f / (float)T_SEQ);
        cwt[threadIdx.x] = cosf(ang);
        swt[threadIdx.x] = sinf(ang);
    }

    const int ww   = threadIdx.x >> 6;
    const int lane = threadIdx.x & 63;
    const int sel  = ww & 3;            // 0=q 1=k 2=v 3=idle
    const int kh   = ww >> 2;           // K-half
    const int rsel = lane & 15;
    const int koff = (lane >> 4) * 8;
    const int tl0g = (lane >> 4) * 4;   // 4-aligned t sub-offset

    f32x4 acc[4][4] = {};
    if (sel < 3) {
        const int n0 = sel * 512 + h * 64;
        const int kb = kh * 256;
        const bf16_t* Ap = X + (m0 + rsel) * EMB + kb + koff;
        const bf16_t* Bp = W + (n0 + rsel) * EMB + kb + koff;
#pragma unroll 4
        for (int k0 = 0; k0 < 256; k0 += 32) {
            bf16x8 af[4], bfr[4];
            for (int i = 0; i < 4; ++i)
                af[i] = *(const bf16x8*)(Ap + i * 16 * EMB + k0);
            for (int j = 0; j < 4; ++j)
                bfr[j] = *(const bf16x8*)(Bp + j * 16 * EMB + k0);
            for (int i = 0; i < 4; ++i)
                for (int j = 0; j < 4; ++j)
                    acc[i][j] = __builtin_amdgcn_mfma_f32_16x16x32_bf16(
                        af[i], bfr[j], acc[i][j], 0, 0, 0);
        }
    }

    // interval 1: second-half v,k waves publish partials (P[feat][t], f32x4)
    if (kh == 1 && (sel == 1 || sel == 2)) {
        float* P = (sel == 2) ? Pa : Pb;
        for (int j = 0; j < 4; ++j)
            for (int i = 0; i < 4; ++i)
                *(f32x4*)(P + (j * 16 + rsel) * LDK + i * 16 + tl0g) = acc[i][j];
    }
    __syncthreads();                                   // B1

    // interval 2: k,v owners reduce + epilogue (sk/sv needed by chunk_sum)
    if (kh == 0 && (sel == 1 || sel == 2)) {
        const float* P = (sel == 2) ? Pa : Pb;
        const int n0 = sel * 512 + h * 64;
        for (int j = 0; j < 4; ++j) {
            const int feat = j * 16 + rsel;
            const float bn = bias[n0 + feat];
            for (int i = 0; i < 4; ++i) {
                const int tl0 = i * 16 + tl0g;
                f32x4 p = *(const f32x4*)(P + feat * LDK + tl0);
                for (int r = 0; r < 4; ++r) {
                    const int tl = tl0 + r;
                    const int t = (m0 & 1023) + tl;
                    float val = acc[i][j][r] + p[r] + bn;
                    int di = ((b * NH + h) * T_SEQ + t) * HD + feat;
                    if (sel == 1) {
                        bf16_t kb2 = (bf16_t)fmaxf(val, 0.f);
                        kk[di] = kb2;
                        sk[tl * LDK + feat] = kb2;
                    } else {
                        bf16_t vb = (bf16_t)val;
                        vv[di] = vb;
                        sv[tl * LDK + feat] = vb;
                    }
                }
            }
        }
    }
    __syncthreads();                                   // B2

    // interval 3: q second-half publishes into Pa (free after B2)
    if (kh == 1 && sel == 0) {
        for (int j = 0; j < 4; ++j)
            for (int i = 0; i < 4; ++i)
                *(f32x4*)(Pa + (j * 16 + rsel) * LDK + i * 16 + tl0g) = acc[i][j];
    }
    __syncthreads();                                   // B3

    // q owner reduces + stores (global only; other waves proceed to chunk_sum)
    if (kh == 0 && sel == 0) {
        const int n0 = h * 64;
        for (int j = 0; j < 4; ++j) {
            const int feat = j * 16 + rsel;
            const float bn = bias[n0 + feat];
            for (int i = 0; i < 4; ++i) {
                const int tl0 = i * 16 + tl0g;
                f32x4 p = *(const f32x4*)(Pa + feat * LDK + tl0);
                for (int r = 0; r < 4; ++r) {
                    const int tl = tl0 + r;
                    const int t = (m0 & 1023) + tl;
                    float val = acc[i][j][r] + p[r] + bn;
                    int di = ((b * NH + h) * T_SEQ + t) * HD + feat;
                    qq[di] = (bf16_t)fmaxf(val, 0.f);
                }
            }
        }
    }

    // ---- chunk_sum body from LDS handoff: 8 waves x 8 v-cols each ----
    const int i  = lane;
    const int jg = ww * 8;
    float ac[8], as[8];
    for (int jj = 0; jj < 8; ++jj) { ac[jj] = 0.f; as[jj] = 0.f; }
    float zca = 0.f, zsa = 0.f;
    const bool zown = (jg == 0);
    for (int t = 0; t < CHUNK; ++t) {
        float kv = (float)sk[t * LDK + i];
        float kc_ = kv * cwt[t];
        float ks_ = kv * swt[t];
        if (zown) { zca += kc_; zsa += ks_; }
        for (int jj = 0; jj < 8; ++jj) {
            float vj = (float)sv[t * LDK + jg + jj];
            ac[jj] += kc_ * vj;
            as[jj] += ks_ * vj;
        }
    }
    bf16_t* oc = Ssc + blk * HD * HD;
    bf16_t* os = Sss + blk * HD * HD;
    for (int jj = 0; jj < 8; ++jj) {
        oc[(jg + jj) * HD + i] = (bf16_t)ac[jj];   // transposed: [e][i]
        os[(jg + jj) * HD + i] = (bf16_t)as[jj];
    }
    if (zown) {
        zc[blk * HD + i] = zca;
        zs[blk * HD + i] = zsa;
    }
}

// ---------------------------------------------------------------------------
// K2: per-chunk output with on-the-fly S/z prefix (unroll-2 prefix loop)
// and the R12 bank-swizzled svT (granule rotation rot(e)=e>>3).
// ---------------------------------------------------------------------------
__global__ __launch_bounds__(256) void chunk_out_kernel(
    const bf16_t* __restrict__ qq, const bf16_t* __restrict__ kk,
    const bf16_t* __restrict__ vv,
    const bf16_t* __restrict__ SscT, const bf16_t* __restrict__ SssT,
    const float* __restrict__ zc, const float* __restrict__ zs,
    bf16_t* __restrict__ Y)
{
    const int blk = blockIdx.x;
    const int bh = blk >> 4, ch = blk & 15;
    __shared__ __align__(16) bf16_t sq [CHUNK * LDA];
    __shared__ __align__(16) bf16_t sk [CHUNK * LDA];
    __shared__ __align__(16) bf16_t svT[CHUNK * LDA];
    __shared__ __align__(16) bf16_t sct[CHUNK * LDA];
    __shared__ __align__(16) bf16_t sst[CHUNK * LDA];
    __shared__ __align__(16) bf16_t sp [CHUNK * LDA];
    __shared__ float cwt[CHUNK], swt[CHUNK], cosd[CHUNK];
    __shared__ float zcl[CHUNK], zsl[CHUNK], nrm[CHUNK];

    const int base = blk * CHUNK * HD;
    for (int i = threadIdx.x; i < CHUNK * HD / 8; i += 256) {
        int row = i >> 3, g = i & 7;
        ((uint4*)(sq + row * LDA))[g]  = ((const uint4*)(qq + base))[i];
        ((uint4*)(sk + row * LDA))[g]  = ((const uint4*)(kk + base))[i];
        // V transpose with granule rotation (conflict-free; see R12)
        bf16x8 v8 = *(const bf16x8*)(vv + base + i * 8);
        int t = i >> 3, bb = i & 7;
        int tg8 = t >> 3, tf = t & 7;
        for (int j = 0; j < 8; ++j) {
            int e = bb * 8 + j;
            int pg = (tg8 + bb) & 7;
            svT[e * LDA + pg * 8 + tf] = v8[j];
        }
    }
    // on-the-fly exclusive prefix of S over chunks < ch (fp32 acc -> bf16 LDS)
    {
        const int e0 = threadIdx.x * 16;            // flat elems [e0, e0+16)
        float accC[16], accS[16];
        for (int j = 0; j < 16; ++j) { accC[j] = 0.f; accS[j] = 0.f; }
        const int sb = bh * NCHUNK * HD * HD + e0;
#pragma unroll 2
        for (int c = 0; c < ch; ++c) {
            const bf16x8* pc = (const bf16x8*)(SscT + sb + c * HD * HD);
            const bf16x8* ps = (const bf16x8*)(SssT + sb + c * HD * HD);
            bf16x8 c0 = pc[0], c1 = pc[1], s0 = ps[0], s1 = ps[1];
            for (int j = 0; j < 8; ++j) {
                accC[j] += (float)c0[j];  accC[8 + j] += (float)c1[j];
                accS[j] += (float)s0[j];  accS[8 + j] += (float)s1[j];
            }
        }
        const int row = threadIdx.x >> 2, col = (threadIdx.x & 3) * 16;
        bf16x8 oc0, oc1, os0, os1;
        for (int j = 0; j < 8; ++j) {
            oc0[j] = (bf16_t)accC[j];  oc1[j] = (bf16_t)accC[8 + j];
            os0[j] = (bf16_t)accS[j];  os1[j] = (bf16_t)accS[8 + j];
        }
        *(bf16x8*)(sct + row * LDA + col) = oc0;
        *(bf16x8*)(sct + row * LDA + col + 8) = oc1;
        *(bf16x8*)(sst + row * LDA + col) = os0;
        *(bf16x8*)(sst + row * LDA + col + 8) = os1;
    }
    // z prefix + angle tables
    if (threadIdx.x < HD) {
        int tl = threadIdx.x;
        float s = 0.f;
        for (int c = 0; c < ch; ++c) s += zc[(bh * NCHUNK + c) * HD + tl];
        zcl[tl] = s;
        int tg = ch * CHUNK + tl;
        float angg = 1.5707963267948966f * (float)tg * (1.0f / (float)T_SEQ);
        cwt[tl] = cosf(angg);
        swt[tl] = sinf(angg);
        cosd[tl] = cosf(1.5707963267948966f * (float)tl * (1.0f / (float)T_SEQ));
    } else if (threadIdx.x < 2 * HD) {
        int i = threadIdx.x - HD;
        float s = 0.f;
        for (int c = 0; c < ch; ++c) s += zs[(bh * NCHUNK + c) * HD + i];
        zsl[i] = s;
    }
    __syncthreads();

    const int w = threadIdx.x >> 6;
    const int lane = threadIdx.x & 63;
    const int rsel = lane & 15;
    const int koff = (lane >> 4) * 8;
    const int myrow = w * 16 + rsel;

    // ---- P = q' k'^T, scale+mask, bf16 rows (wave-local) ----
    bf16x8 aq0 = *(const bf16x8*)(sq + myrow * LDA + koff);
    bf16x8 aq1 = *(const bf16x8*)(sq + myrow * LDA + koff + 32);
    for (int nt = 0; nt < 4; ++nt) {
        const int n0 = nt * 16;
        f32x4 pacc = {0.f, 0.f, 0.f, 0.f};
        bf16x8 b0 = *(const bf16x8*)(sk + (n0 + rsel) * LDA + koff);
        bf16x8 b1 = *(const bf16x8*)(sk + (n0 + rsel) * LDA + koff + 32);
        pacc = __builtin_amdgcn_mfma_f32_16x16x32_bf16(aq0, b0, pacc, 0, 0, 0);
        pacc = __builtin_amdgcn_mfma_f32_16x16x32_bf16(aq1, b1, pacc, 0, 0, 0);
        const int s = n0 + (lane & 15);
        const int tb = w * 16 + (lane >> 4) * 4;
        for (int r = 0; r < 4; ++r) {
            int t = tb + r;
            float p = (s <= t) ? pacc[r] * cosd[t - s] : 0.f;
            sp[t * LDA + s] = (bf16_t)p;
        }
    }

    // ---- nrm (lanes 0..15 of each wave; rows wave-local) ----
    if (lane < 16) {
        int row = w * 16 + lane;
        float nv = 0.f;
        const bf16x8* pr = (const bf16x8*)(sp + row * LDA);
        for (int g = 0; g < 8; ++g) {
            bf16x8 pv = pr[g];
            for (int j = 0; j < 8; ++j) nv += (float)pv[j];
        }
        float cwr = cwt[row], swr = swt[row];
        const bf16x8* qr = (const bf16x8*)(sq + row * LDA);
        for (int g = 0; g < 8; ++g) {
            bf16x8 qv = qr[g];
            for (int j = 0; j < 8; ++j)
                nv += (float)qv[j] * (cwr * zcl[g * 8 + j] + swr * zsl[g * 8 + j]);
        }
        nrm[row] = nv;
    }

    // ---- ctx = P@V + q'c@Sc + q's@Ss ----
    const float cwq = cwt[myrow], swq = swt[myrow];
    bf16x8 qc0, qc1, qs0, qs1;
    for (int j = 0; j < 8; ++j) {
        qc0[j] = (bf16_t)((float)aq0[j] * cwq);
        qc1[j] = (bf16_t)((float)aq1[j] * cwq);
        qs0[j] = (bf16_t)((float)aq0[j] * swq);
        qs1[j] = (bf16_t)((float)aq1[j] * swq);
    }
    bf16x8 ap0 = *(const bf16x8*)(sp + myrow * LDA + koff);
    bf16x8 ap1 = *(const bf16x8*)(sp + myrow * LDA + koff + 32);

    const int b = bh >> 3, h = bh & 7;
    const int g0 = koff >> 3;                       // logical granule 0..3
    for (int nt = 0; nt < 4; ++nt) {
        const int n0 = nt * 16;
        const int ee = n0 + rsel;
        const int rot = (ee >> 3) & 7;
        const bf16_t* bvp0 = svT + ee * LDA + (((g0 + rot) & 7) << 3);
        const bf16_t* bvp1 = svT + ee * LDA + (((g0 + 4 + rot) & 7) << 3);
        const bf16_t* bcp = sct + ee * LDA + koff;
        const bf16_t* bsp = sst + ee * LDA + koff;
        f32x4 acc = {0.f, 0.f, 0.f, 0.f};
        acc = __builtin_amdgcn_mfma_f32_16x16x32_bf16(ap0, *(const bf16x8*)(bvp0), acc, 0, 0, 0);
        acc = __builtin_amdgcn_mfma_f32_16x16x32_bf16(ap1, *(const bf16x8*)(bvp1), acc, 0, 0, 0);
        acc = __builtin_amdgcn_mfma_f32_16x16x32_bf16(qc0, *(const bf16x8*)(bcp), acc, 0, 0, 0);
        acc = __builtin_amdgcn_mfma_f32_16x16x32_bf16(qc1, *(const bf16x8*)(bcp + 32), acc, 0, 0, 0);
        acc = __builtin_amdgcn_mfma_f32_16x16x32_bf16(qs0, *(const bf16x8*)(bsp), acc, 0, 0, 0);
        acc = __builtin_amdgcn_mfma_f32_16x16x32_bf16(qs1, *(const bf16x8*)(bsp + 32), acc, 0, 0, 0);
        const int col = n0 + (lane & 15);
        const int tb = w * 16 + (lane >> 4) * 4;
        for (int r = 0; r < 4; ++r) {
            int row = tb + r;
            float inv = 1.0f / (nrm[row] + 1e-6f);
            int tg = ch * CHUNK + row;
            Y[((b * T_SEQ + tg) * EMB) + h * HD + col] = (bf16_t)(acc[r] * inv);
        }
    }
}

// ---------------------------------------------------------------------------
// K3: out = Y @ w_out^T + b_out. 256 blocks of 512 threads: 8 waves =
// quadrant (w&3: m-half/n-half) x K-half (w>>2). Each wave: 32x32 tile,
// acc[2][2], K=256 (8 k-iters). kh=1 publishes f32 partials to LDS
// (col-major stride-36 f32 -> 16B-aligned f32x4); 1 barrier; kh=0 adds,
// bias, stores. Load count per block unchanged (256 instrs).
// ---------------------------------------------------------------------------
#define POG 1152            // per-quadrant floats: 32 cols * 36
__global__ __launch_bounds__(512) void out_gemm_kernel(
    const bf16_t* __restrict__ Yb, const bf16_t* __restrict__ W,
    const float* __restrict__ bias, float* __restrict__ out)
{
    __shared__ __align__(16) float P[4 * POG];
    const int w = threadIdx.x >> 6;
    const int lane = threadIdx.x & 63;
    const int qd = w & 3;           // quadrant: m-half = qd&1, n-half = qd>>1
    const int kh = w >> 2;          // K-half
    const int rsel = lane & 15;
    const int koff = (lane >> 4) * 8;
    const int m0 = blockIdx.x * 64 + (qd & 1) * 32;
    const int n0 = blockIdx.y * 64 + (qd >> 1) * 32;
    const int kb = kh * 256;
    f32x4 acc[2][2] = {};
    const bf16_t* Ap = Yb + (m0 + rsel) * EMB + kb + koff;
    const bf16_t* Bp = W + (n0 + rsel) * EMB + kb + koff;
#pragma unroll 4
    for (int k0 = 0; k0 < 256; k0 += 32) {
        bf16x8 af[2], bfr[2];
        for (int i = 0; i < 2; ++i)
            af[i] = *(const bf16x8*)(Ap + i * 16 * EMB + k0);
        for (int j = 0; j < 2; ++j)
            bfr[j] = *(const bf16x8*)(Bp + j * 16 * EMB + k0);
        for (int i = 0; i < 2; ++i)
            for (int j = 0; j < 2; ++j)
                acc[i][j] = __builtin_amdgcn_mfma_f32_16x16x32_bf16(
                    af[i], bfr[j], acc[i][j], 0, 0, 0);
    }
    float* Pq = P + qd * POG;
    const int rowb = (lane >> 4) * 4;               // 4-aligned local row base
    if (kh == 1) {
        for (int j = 0; j < 2; ++j)
            for (int i = 0; i < 2; ++i)
                *(f32x4*)(Pq + (j * 16 + rsel) * 36 + i * 16 + rowb) = acc[i][j];
    }
    __syncthreads();
    if (kh == 0) {
        for (int j = 0; j < 2; ++j) {
            const int n = n0 + j * 16 + rsel;
            const float bn = bias[n];
            for (int i = 0; i < 2; ++i) {
                f32x4 p = *(const f32x4*)(Pq + (j * 16 + rsel) * 36 + i * 16 + rowb);
                const int mb = m0 + i * 16 + rowb;
                for (int r = 0; r < 4; ++r)
                    out[(mb + r) * EMB + n] = acc[i][j][r] + p[r] + bn;
            }
        }
    }
}

extern "C" void kernel_launch(void* const* d_in, const int* in_sizes, int n_in,
                              void* d_out, int out_size, void* d_ws, size_t ws_size,
                              hipStream_t stream) {
    const float* x     = (const float*)d_in[0];
    const float* w_qkv = (const float*)d_in[1];
    const float* b_qkv = (const float*)d_in[2];
    const float* w_out = (const float*)d_in[3];
    const float* b_out = (const float*)d_in[4];
    float* out = (float*)d_out;

    char* w = (char*)d_ws;
    const size_t N_X   = (size_t)BATCH * T_SEQ * EMB;
    const size_t N_WQ  = (size_t)3 * EMB * EMB;
    const size_t N_WO  = (size_t)EMB * EMB;
    bf16_t* xb   = (bf16_t*)w;                 w += N_X  * sizeof(bf16_t);
    bf16_t* wqb  = (bf16_t*)w;                 w += N_WQ * sizeof(bf16_t);
    bf16_t* wob  = (bf16_t*)w;                 w += N_WO * sizeof(bf16_t);
    const size_t SZ_BHTD = (size_t)NBH * T_SEQ * HD * sizeof(bf16_t);
    bf16_t* qq = (bf16_t*)w;                   w += SZ_BHTD;
    bf16_t* kk = (bf16_t*)w;                   w += SZ_BHTD;
    bf16_t* vv = (bf16_t*)w;                   w += SZ_BHTD;
    bf16_t* Y  = (bf16_t*)w;                   w += SZ_BHTD;
    bf16_t* SscT = (bf16_t*)w;                 w += (size_t)NBLK * HD * HD * sizeof(bf16_t);
    bf16_t* SssT = (bf16_t*)w;                 w += (size_t)NBLK * HD * HD * sizeof(bf16_t);
    float* zc = (float*)w;                     w += (size_t)NBLK * HD * sizeof(float);
    float* zs = (float*)w;

    cvt3_kernel<<<2048, 256, 0, stream>>>(x, w_qkv, w_out, xb, wqb, wob);
    qkv_sum_kernel<<<dim3(32, 8), 512, 0, stream>>>(
        xb, wqb, b_qkv, qq, kk, vv, SscT, SssT, zc, zs);
    chunk_out_kernel<<<NBLK, 256, 0, stream>>>(qq, kk, vv, SscT, SssT, zc, zs, Y);
    out_gemm_kernel<<<dim3(2048 / 64, 512 / 64), 512, 0, stream>>>(
        Y, wob, b_out, out);
}